// Round 5
// baseline (742.332 us; speedup 1.0000x reference)
//
#include <hip/hip_runtime.h>
#include <hip/hip_bf16.h>
#include <cstdio>

// ---------------------------------------------------------------------------
// Attn_59940563583594: hidden[32,1024,768] -> QKV -> causal attn (no 1/sqrt(d))
//                      -> relu MLP(768->64) -> out[32,1024,2] fp32
// Numerics (verified R2-R4: absmax 9.8e-4 vs 3.8e-3 threshold):
//   f16 storage/MFMA for hidden/W/q/k, no-max softmax (exp clamp 80,
//   unnormalized bf16 p, fp32 row sums, normalize in PV), bf16 PV + MLP.
// R5: R4 showed the QKV GEMMs saturate the vmem path (~7 TB/s logical) by
//   re-reading h16 6x per n-column and 3x per z (FETCH 6x ideal). Merge
//   q/k/v into one kernel, n-tile loop INSIDE the block: A-tile (0.19 MB)
//   stays hot in L2 across the 6 n-tiles, W (4.5 MB) is L2-resident, and
//   h16 streams from HBM ~once. z is the fastest grid dim so co-resident
//   blocks of one m-tile share the A-tile in L2.
// ---------------------------------------------------------------------------

typedef _Float16 f16;
typedef f16    f16x8 __attribute__((ext_vector_type(8)));
typedef f16    f16x4 __attribute__((ext_vector_type(4)));
typedef __bf16 bfx8  __attribute__((ext_vector_type(8)));
typedef float  f32x4 __attribute__((ext_vector_type(4)));

#define MFMA_F16(a,b,c)  __builtin_amdgcn_mfma_f32_16x16x32_f16((a),(b),(c),0,0,0)
#define MFMA_BF16(a,b,c) __builtin_amdgcn_mfma_f32_16x16x32_bf16((a),(b),(c),0,0,0)

static constexpr int LDT = 136;  // v-transpose buffer stride

__device__ __forceinline__ void gl_lds16(const void* g, void* l) {
    __builtin_amdgcn_global_load_lds(
        (const __attribute__((address_space(1))) void*)g,
        (__attribute__((address_space(3))) void*)l, 16, 0, 0);
}

// ---------------- fp32 -> f16 converts --------------------------------------
__global__ __launch_bounds__(256) void cvt_f32_f16(
    const float* __restrict__ x, f16* __restrict__ y, int n)
{
    int base = (blockIdx.x * 256 + threadIdx.x) * 4;
    if (base >= n) return;
    f32x4 v = *(const f32x4*)(x + base);
    f16x4 o;
    #pragma unroll
    for (int e = 0; e < 4; ++e) o[e] = (f16)v[e];
    *(f16x4*)(y + base) = o;
}

__global__ __launch_bounds__(256) void cvt3_w(
    const float* __restrict__ Wq, const float* __restrict__ Wk, const float* __restrict__ Wv,
    f16* __restrict__ oq, f16* __restrict__ ok, f16* __restrict__ ov)
{
    const int z = blockIdx.y;
    const float* s = (z == 0) ? Wq : (z == 1) ? Wk : Wv;
    f16* d = (z == 0) ? oq : (z == 1) ? ok : ov;
    int base = (blockIdx.x * 256 + threadIdx.x) * 4;
    f32x4 v = *(const f32x4*)(s + base);
    f16x4 o;
    #pragma unroll
    for (int e = 0; e < 4; ++e) o[e] = (f16)v[e];
    *(f16x4*)(d + base) = o;
}

// ---------------- K1: fused q,k,v projections (f16 NT GEMM) -----------------
// grid (z=3, m=256); block loops the 6 n-tiles so A stays hot in L2.
__global__ __launch_bounds__(256) void qkv_kernel(
    const f16* __restrict__ h16,
    const f16* __restrict__ wq, const f16* __restrict__ wk, const f16* __restrict__ wv,
    const float* __restrict__ bq, const float* __restrict__ bk, const float* __restrict__ bv,
    f16* __restrict__ q16, f16* __restrict__ k16, __bf16* __restrict__ vT)
{
    const int z = blockIdx.x;
    const f16* W = (z == 0) ? wq : (z == 1) ? wk : wv;
    const float* bias = (z == 0) ? bq : (z == 1) ? bk : bv;

    __shared__ alignas(16) char smem[34816];         // max(32KB dbuf, 34KB Tb)
    f16 (*As)[4096] = (f16(*)[4096])smem;            // [2][128*32]
    f16 (*Bs)[4096] = (f16(*)[4096])(smem + 16384);
    __bf16* Tb = (__bf16*)smem;                      // aliased, z==2 epilogue only

    const int t = threadIdx.x, lane = t & 63, wave = t >> 6;
    const int wm = (wave & 1) * 64, wn = (wave >> 1) * 64;
    const int quad = lane >> 4, l16 = lane & 15;
    const int m0 = blockIdx.y * 128;
    const int c0 = wave * 2, c1 = c0 + 1;
    // staging: lane i -> (row = c*16 + (i&15), col chunk = (i>>4)*8)
    const f16* ga0 = &h16[(size_t)(m0 + c0 * 16 + l16) * 768 + quad * 8];
    const f16* ga1 = &h16[(size_t)(m0 + c1 * 16 + l16) * 768 + quad * 8];

    for (int nt = 0; nt < 6; ++nt) {
        const int n0 = nt * 128;
        const f16* gb0 = &W[(size_t)(n0 + c0 * 16 + l16) * 768 + quad * 8];
        const f16* gb1 = &W[(size_t)(n0 + c1 * 16 + l16) * 768 + quad * 8];

        f32x4 acc[4][4] = {};
        auto stage = [&](int k0, int buf) {
            gl_lds16(ga0 + k0, &As[buf][c0 * 512]);
            gl_lds16(ga1 + k0, &As[buf][c1 * 512]);
            gl_lds16(gb0 + k0, &Bs[buf][c0 * 512]);
            gl_lds16(gb1 + k0, &Bs[buf][c1 * 512]);
        };
        auto compute = [&](int buf) {
            f16x8 af[4], bg[4];
            #pragma unroll
            for (int i = 0; i < 4; ++i) {
                af[i] = *(const f16x8*)&As[buf][(wm / 16 + i) * 512 + quad * 128 + l16 * 8];
                bg[i] = *(const f16x8*)&Bs[buf][(wn / 16 + i) * 512 + quad * 128 + l16 * 8];
            }
            #pragma unroll
            for (int i = 0; i < 4; ++i)
                #pragma unroll
                for (int j = 0; j < 4; ++j)
                    acc[i][j] = MFMA_F16(af[i], bg[j], acc[i][j]);
        };

        __syncthreads();          // prior nt's LDS use (incl. Tb) fully done
        stage(0, 0);
        int cur = 0;
        for (int k0 = 32; k0 < 768; k0 += 32) {
            __syncthreads();      // buf[cur] published; prior buf free
            stage(k0, cur ^ 1);   // flies during compute
            compute(cur);
            cur ^= 1;
        }
        __syncthreads();
        compute(cur);

        if (z < 2) {
            f16* out = z ? k16 : q16;
            #pragma unroll
            for (int j = 0; j < 4; ++j) {
                int col = n0 + wn + j * 16 + l16;
                float bb = bias[col];
                #pragma unroll
                for (int i = 0; i < 4; ++i)
                    #pragma unroll
                    for (int r = 0; r < 4; ++r) {
                        int row = m0 + wm + i * 16 + quad * 4 + r;  // D: col=lane&15, row=quad*4+reg
                        out[(size_t)row * 768 + col] = (f16)(acc[i][j][r] + bb);
                    }
            }
        } else {
            __syncthreads();  // all waves done reading As/Bs before Tb overwrite
            #pragma unroll
            for (int j = 0; j < 4; ++j) {
                int el = wn + j * 16 + l16;
                float bb = bias[n0 + el];
                #pragma unroll
                for (int i = 0; i < 4; ++i)
                    #pragma unroll
                    for (int r = 0; r < 4; ++r) {
                        int sl = wm + i * 16 + quad * 4 + r;
                        Tb[el * LDT + sl] = (__bf16)(acc[i][j][r] + bb);
                    }
            }
            __syncthreads();
            const size_t bofs = (size_t)(m0 >> 10) * 768;
            const int s0 = m0 & 1023;
            const int ch = (t & 15) * 8;
            #pragma unroll
            for (int p = 0; p < 8; ++p) {
                int r = (t >> 4) + p * 16;
                bfx8 val = *(const bfx8*)&Tb[r * LDT + ch];
                *(bfx8*)&vT[(bofs + n0 + r) * 1024 + s0 + ch] = val;
            }
        }
    }
}

// ---------------- K2: p_u = exp(q@k^T + mask), bf16; fp32 rowsum partials ---
__global__ __launch_bounds__(256) void logits_kernel(
    const f16* __restrict__ q16, const f16* __restrict__ k16,
    const float* __restrict__ amask, __bf16* __restrict__ pu, float* __restrict__ psum)
{
    const int b = blockIdx.z, nt = blockIdx.x;
    const int m0 = blockIdx.y * 128, n0 = nt * 128;
    const int t = threadIdx.x;
    const size_t pb = (size_t)b << 20;

    if (n0 > m0) {  // fully masked tile: p = 0 exactly
        int r = t >> 1, half = t & 1;
        bfx8 zv;
        #pragma unroll
        for (int e = 0; e < 8; ++e) zv[e] = (__bf16)0.f;
        #pragma unroll
        for (int c = 0; c < 8; ++c)
            *(bfx8*)&pu[pb + (size_t)(m0 + r) * 1024 + n0 + half * 64 + c * 8] = zv;
        if (t < 128) psum[((size_t)b * 1024 + m0 + t) * 8 + nt] = 0.f;
        return;
    }

    __shared__ alignas(16) char smem[32768];
    f16 (*As)[4096] = (f16(*)[4096])smem;
    f16 (*Bs)[4096] = (f16(*)[4096])(smem + 16384);
    __shared__ float rs[2][128];

    const int lane = t & 63, wave = t >> 6;
    const int wm = (wave & 1) * 64, wn = (wave >> 1) * 64;
    const int quad = lane >> 4, l16 = lane & 15;
    const size_t qb = (size_t)b * 1024 * 768;
    const int c0 = wave * 2, c1 = c0 + 1;
    const f16* ga0 = &q16[qb + (size_t)(m0 + c0 * 16 + l16) * 768 + quad * 8];
    const f16* ga1 = &q16[qb + (size_t)(m0 + c1 * 16 + l16) * 768 + quad * 8];
    const f16* gb0 = &k16[qb + (size_t)(n0 + c0 * 16 + l16) * 768 + quad * 8];
    const f16* gb1 = &k16[qb + (size_t)(n0 + c1 * 16 + l16) * 768 + quad * 8];

    f32x4 acc[4][4] = {};
    auto stage = [&](int k0, int buf) {
        gl_lds16(ga0 + k0, &As[buf][c0 * 512]);
        gl_lds16(ga1 + k0, &As[buf][c1 * 512]);
        gl_lds16(gb0 + k0, &Bs[buf][c0 * 512]);
        gl_lds16(gb1 + k0, &Bs[buf][c1 * 512]);
    };
    auto compute = [&](int buf) {
        f16x8 af[4], bg[4];
        #pragma unroll
        for (int i = 0; i < 4; ++i) {
            af[i] = *(const f16x8*)&As[buf][(wm / 16 + i) * 512 + quad * 128 + l16 * 8];
            bg[i] = *(const f16x8*)&Bs[buf][(wn / 16 + i) * 512 + quad * 128 + l16 * 8];
        }
        #pragma unroll
        for (int i = 0; i < 4; ++i)
            #pragma unroll
            for (int j = 0; j < 4; ++j)
                acc[i][j] = MFMA_F16(af[i], bg[j], acc[i][j]);
    };

    stage(0, 0);
    int cur = 0;
    for (int k0 = 32; k0 < 768; k0 += 32) {
        __syncthreads();
        stage(k0, cur ^ 1);
        compute(cur);
        cur ^= 1;
    }
    __syncthreads();
    compute(cur);

    float rp[4][4] = {};
    #pragma unroll
    for (int j = 0; j < 4; ++j) {
        int col = n0 + wn + j * 16 + l16;
        float am = (1.0f - amask[b * 1024 + col]) * -10000.0f;
        #pragma unroll
        for (int i = 0; i < 4; ++i)
            #pragma unroll
            for (int r = 0; r < 4; ++r) {
                int row = m0 + wm + i * 16 + quad * 4 + r;
                float s = acc[i][j][r] + am;
                float pval = (col <= row) ? __expf(fminf(s, 80.0f)) : 0.0f;
                pu[pb + (size_t)row * 1024 + col] = (__bf16)pval;
                rp[i][r] += pval;
            }
    }
    #pragma unroll
    for (int i = 0; i < 4; ++i)
        #pragma unroll
        for (int r = 0; r < 4; ++r) {
            float v = rp[i][r];
            v += __shfl_xor(v, 1, 64);
            v += __shfl_xor(v, 2, 64);
            v += __shfl_xor(v, 4, 64);
            v += __shfl_xor(v, 8, 64);
            if (l16 == 0) rs[wn >> 6][wm + i * 16 + quad * 4 + r] = v;
        }
    __syncthreads();
    if (t < 128)
        psum[((size_t)b * 1024 + m0 + t) * 8 + nt] = rs[0][t] + rs[1][t];
}

// ---------------- K3: h = (p_u @ v) / rowsum, bf16 --------------------------
__global__ __launch_bounds__(256) void pv_kernel(
    const __bf16* __restrict__ pu, const __bf16* __restrict__ vT,
    const float* __restrict__ psum, __bf16* __restrict__ h)
{
    const int b = blockIdx.z;
    const int m0 = blockIdx.y * 128, n0 = blockIdx.x * 128;
    const int t = threadIdx.x, lane = t & 63, wave = t >> 6;
    const int wm = (wave & 1) * 64, wn = (wave >> 1) * 64;
    const int quad = lane >> 4, l16 = lane & 15;
    const size_t pb = (size_t)b << 20;
    const size_t vb = (size_t)b * 768 * 1024;

    __shared__ alignas(16) char smem[32768];
    __bf16 (*As)[4096] = (__bf16(*)[4096])smem;
    __bf16 (*Bs)[4096] = (__bf16(*)[4096])(smem + 16384);
    __shared__ float invl[128];

    if (t < 128) {
        const float* pr = &psum[((size_t)b * 1024 + m0 + t) * 8];
        f32x4 a = *(const f32x4*)pr, c = *(const f32x4*)(pr + 4);
        invl[t] = 1.0f / (a[0] + a[1] + a[2] + a[3] + c[0] + c[1] + c[2] + c[3]);
    }

    const int c0 = wave * 2, c1 = c0 + 1;
    const __bf16* ga0 = &pu[pb + (size_t)(m0 + c0 * 16 + l16) * 1024 + quad * 8];
    const __bf16* ga1 = &pu[pb + (size_t)(m0 + c1 * 16 + l16) * 1024 + quad * 8];
    const __bf16* gb0 = &vT[vb + (size_t)(n0 + c0 * 16 + l16) * 1024 + quad * 8];
    const __bf16* gb1 = &vT[vb + (size_t)(n0 + c1 * 16 + l16) * 1024 + quad * 8];

    f32x4 acc[4][4] = {};
    auto stage = [&](int k0, int buf) {
        gl_lds16(ga0 + k0, &As[buf][c0 * 512]);
        gl_lds16(ga1 + k0, &As[buf][c1 * 512]);
        gl_lds16(gb0 + k0, &Bs[buf][c0 * 512]);
        gl_lds16(gb1 + k0, &Bs[buf][c1 * 512]);
    };
    auto compute = [&](int buf) {
        bfx8 af[4], bg[4];
        #pragma unroll
        for (int i = 0; i < 4; ++i) {
            af[i] = *(const bfx8*)&As[buf][(wm / 16 + i) * 512 + quad * 128 + l16 * 8];
            bg[i] = *(const bfx8*)&Bs[buf][(wn / 16 + i) * 512 + quad * 128 + l16 * 8];
        }
        #pragma unroll
        for (int i = 0; i < 4; ++i)
            #pragma unroll
            for (int j = 0; j < 4; ++j)
                acc[i][j] = MFMA_BF16(af[i], bg[j], acc[i][j]);
    };

    const int kend = m0 + 128;  // p_u is exactly 0 above the diagonal
    stage(0, 0);
    int cur = 0;
    for (int k0 = 32; k0 < kend; k0 += 32) {
        __syncthreads();
        stage(k0, cur ^ 1);
        compute(cur);
        cur ^= 1;
    }
    __syncthreads();
    compute(cur);

    #pragma unroll
    for (int j = 0; j < 4; ++j) {
        int col = n0 + wn + j * 16 + l16;
        #pragma unroll
        for (int i = 0; i < 4; ++i)
            #pragma unroll
            for (int r = 0; r < 4; ++r) {
                int rl = wm + i * 16 + quad * 4 + r;
                h[((size_t)b * 1024 + m0 + rl) * 768 + col] = (__bf16)(acc[i][j][r] * invl[rl]);
            }
    }
}

// ---------------- K4: out = relu(h @ W1^T + b1) @ W2^T + b2 -----------------
__global__ __launch_bounds__(256) void mlp_kernel(
    const __bf16* __restrict__ h, const float* __restrict__ W1, const float* __restrict__ b1,
    const float* __restrict__ W2, const float* __restrict__ b2, float* __restrict__ out)
{
    const int wave = threadIdx.x >> 6, lane = threadIdx.x & 63;
    const int quad = lane >> 4, l16 = lane & 15;
    const int m0 = blockIdx.x * 64 + wave * 16;

    f32x4 acc[4] = {};
    for (int k0 = 0; k0 < 768; k0 += 32) {
        bfx8 af = *(const bfx8*)&h[(size_t)(m0 + l16) * 768 + k0 + quad * 8];
        #pragma unroll
        for (int j = 0; j < 4; ++j) {
            const float* wp = W1 + (size_t)(j * 16 + l16) * 768 + k0 + quad * 8;
            f32x4 w0 = *(const f32x4*)wp;
            f32x4 w1 = *(const f32x4*)(wp + 4);
            bfx8 bg;
            #pragma unroll
            for (int e = 0; e < 4; ++e) { bg[e] = (__bf16)w0[e]; bg[e + 4] = (__bf16)w1[e]; }
            acc[j] = MFMA_BF16(af, bg, acc[j]);
        }
    }
    float part[4][2] = {};
    #pragma unroll
    for (int j = 0; j < 4; ++j) {
        int c = j * 16 + l16;
        float bb = b1[c];
        float w20 = W2[c], w21 = W2[64 + c];
        #pragma unroll
        for (int r = 0; r < 4; ++r) {
            float x = fmaxf(acc[j][r] + bb, 0.f);
            part[r][0] += x * w20;
            part[r][1] += x * w21;
        }
    }
    #pragma unroll
    for (int off = 1; off < 16; off <<= 1)
        #pragma unroll
        for (int r = 0; r < 4; ++r) {
            part[r][0] += __shfl_xor(part[r][0], off, 64);
            part[r][1] += __shfl_xor(part[r][1], off, 64);
        }
    if (l16 == 0) {
        #pragma unroll
        for (int r = 0; r < 4; ++r) {
            int row = m0 + quad * 4 + r;
            out[(size_t)row * 2 + 0] = part[r][0] + b2[0];
            out[(size_t)row * 2 + 1] = part[r][1] + b2[1];
        }
    }
}

// ---------------------------------------------------------------------------
extern "C" void kernel_launch(void* const* d_in, const int* in_sizes, int n_in,
                              void* d_out, int out_size, void* d_ws, size_t ws_size,
                              hipStream_t stream)
{
    const float* hidden = (const float*)d_in[0];
    const float* amask  = (const float*)d_in[1];
    const float* Wk = (const float*)d_in[2];
    const float* bk = (const float*)d_in[3];
    const float* Wq = (const float*)d_in[4];
    const float* bq = (const float*)d_in[5];
    const float* Wv = (const float*)d_in[6];
    const float* bv = (const float*)d_in[7];
    const float* W1 = (const float*)d_in[8];
    const float* b1 = (const float*)d_in[9];
    const float* W2 = (const float*)d_in[10];
    const float* b2 = (const float*)d_in[11];
    float* out = (float*)d_out;

    char* ws = (char*)d_ws;
    const size_t MB = 1024 * 1024;
    // Phase 1 (qkv): h16 @0 (48MB), w16 @48MB (3.4MB)  [dead after qkv]
    // Phase 2 (logits): pu @0 (64MB, aliases phase1), psum @64MB (1MB)
    // q16 @66MB (48), k16 @114MB (48), vT @162MB (48)
    // Phase 3 (pv/mlp): h @66MB (aliases q16, dead after logits)
    f16* h16 = (f16*)ws;
    f16* wq16 = (f16*)(ws + 48 * MB);
    f16* wk16 = wq16 + 589824;
    f16* wv16 = wk16 + 589824;
    __bf16* pu  = (__bf16*)ws;
    float*  psum = (float*)(ws + 64 * MB);
    f16* q16 = (f16*)(ws + 66 * MB);
    f16* k16 = (f16*)(ws + 114 * MB);
    __bf16* vT = (__bf16*)(ws + 162 * MB);
    __bf16* h  = (__bf16*)(ws + 66 * MB);
    const size_t NEED = 210 * MB;
    if (ws_size < NEED) {
        fprintf(stderr, "[Attn kernel] ws too small: %zu < %zu — skipping launches\n",
                ws_size, NEED);
        return;
    }

    cvt_f32_f16<<<24576, 256, 0, stream>>>(hidden, h16, 25165824);
    cvt3_w<<<dim3(576, 3), 256, 0, stream>>>(Wq, Wk, Wv, wq16, wk16, wv16);

    qkv_kernel<<<dim3(3, 256), 256, 0, stream>>>(
        h16, wq16, wk16, wv16, bq, bk, bv, q16, k16, vT);
    logits_kernel<<<dim3(8, 8, 32), 256, 0, stream>>>(q16, k16, amask, pu, psum);
    pv_kernel<<<dim3(6, 8, 32), 256, 0, stream>>>(pu, vT, psum, h);
    mlp_kernel<<<512, 256, 0, stream>>>(h, W1, b1, W2, b2, out);
}

// Round 6
// 619.551 us; speedup vs baseline: 1.1982x; 1.1982x over previous
//
#include <hip/hip_runtime.h>
#include <hip/hip_bf16.h>
#include <cstdio>

// ---------------------------------------------------------------------------
// Attn_59940563583594: hidden[32,1024,768] -> QKV -> causal attn (no 1/sqrt(d))
//                      -> relu MLP(768->64) -> out[32,1024,2] fp32
// Numerics (verified R2-R5: absmax 9.8e-4 vs 3.8e-3 threshold):
//   f16 storage/MFMA for hidden/W/q/k, no-max softmax (exp clamp 80,
//   unnormalized bf16 p, fp32 row sums, normalize in PV), bf16 PV + MLP.
// R6: QKV as 256x128-tile GEMM (87.5 FLOP/staged-byte, was 65.5) + XCD-aware
//   swizzle (block->XCD = id%8 round-robin assumption): m-tiles partitioned
//   per XCD so h16 streams from HBM once and W stays L2-resident. R5's
//   nt-inside-block is reverted (it cut parallelism, not bytes).
// ---------------------------------------------------------------------------

typedef _Float16 f16;
typedef f16    f16x8 __attribute__((ext_vector_type(8)));
typedef f16    f16x4 __attribute__((ext_vector_type(4)));
typedef __bf16 bfx8  __attribute__((ext_vector_type(8)));
typedef float  f32x4 __attribute__((ext_vector_type(4)));

#define MFMA_F16(a,b,c)  __builtin_amdgcn_mfma_f32_16x16x32_f16((a),(b),(c),0,0,0)
#define MFMA_BF16(a,b,c) __builtin_amdgcn_mfma_f32_16x16x32_bf16((a),(b),(c),0,0,0)

static constexpr int LDT = 136;  // v-transpose buffer stride (bf16)

__device__ __forceinline__ void gl_lds16(const void* g, void* l) {
    __builtin_amdgcn_global_load_lds(
        (const __attribute__((address_space(1))) void*)g,
        (__attribute__((address_space(3))) void*)l, 16, 0, 0);
}

// ---------------- fp32 -> f16 converts --------------------------------------
__global__ __launch_bounds__(256) void cvt_f32_f16(
    const float* __restrict__ x, f16* __restrict__ y, int n)
{
    int base = (blockIdx.x * 256 + threadIdx.x) * 4;
    if (base >= n) return;
    f32x4 v = *(const f32x4*)(x + base);
    f16x4 o;
    #pragma unroll
    for (int e = 0; e < 4; ++e) o[e] = (f16)v[e];
    *(f16x4*)(y + base) = o;
}

__global__ __launch_bounds__(256) void cvt3_w(
    const float* __restrict__ Wq, const float* __restrict__ Wk, const float* __restrict__ Wv,
    f16* __restrict__ oq, f16* __restrict__ ok, f16* __restrict__ ov)
{
    const int z = blockIdx.y;
    const float* s = (z == 0) ? Wq : (z == 1) ? Wk : Wv;
    f16* d = (z == 0) ? oq : (z == 1) ? ok : ov;
    int base = (blockIdx.x * 256 + threadIdx.x) * 4;
    f32x4 v = *(const f32x4*)(s + base);
    f16x4 o;
    #pragma unroll
    for (int e = 0; e < 4; ++e) o[e] = (f16)v[e];
    *(f16x4*)(d + base) = o;
}

// ---------------- K1: fused q,k,v projections, 256x128 tiles ----------------
// 2304 blocks of 512 threads. Block id decodes XCD-aware:
//   xcd=id%8, j=id/8; nt=j%6 (fastest), z=(j/6)%3, mi=j/18, mt=xcd+8*mi.
// Each XCD owns m-tiles {xcd, xcd+8, ...}: reads 6 MB of h16 + 3.4 MB W.
__global__ __launch_bounds__(512, 4) void qkv_kernel(
    const f16* __restrict__ h16,
    const f16* __restrict__ wq, const f16* __restrict__ wk, const f16* __restrict__ wv,
    const float* __restrict__ bq, const float* __restrict__ bk, const float* __restrict__ bv,
    f16* __restrict__ q16, f16* __restrict__ k16, __bf16* __restrict__ vT)
{
    const int f = blockIdx.x;
    const int xcd = f & 7;
    const int j = f >> 3;
    const int nt = j % 6;
    const int z  = (j / 6) % 3;
    const int mi = j / 18;
    const int mt = xcd + 8 * mi;
    const int m0 = mt * 256, n0 = nt * 128;

    const f16* W = (z == 0) ? wq : (z == 1) ? wk : wv;
    const float* bias = (z == 0) ? bq : (z == 1) ? bk : bv;

    // [buf][24 chunks * 512 f16]: chunks 0..15 = A (256 rows), 16..23 = B (128)
    __shared__ alignas(16) f16 S[2][24 * 512];          // 48 KB
    __bf16* Tb = (__bf16*)&S[0][0];                     // aliased, z==2 epilogue

    const int t = threadIdx.x, lane = t & 63, wave = t >> 6;
    const int wm = (wave & 3) * 64, wn = (wave >> 2) * 64;
    const int quad = lane >> 4, l16 = lane & 15;

    // staging: chunk = 16 rows x 32 cols; lane i -> (row=i&15, colchunk=i>>4)
    const f16* gsrc[3];
    int ldst[3];
    #pragma unroll
    for (int u = 0; u < 3; ++u) {
        int c = wave * 3 + u;
        ldst[u] = c * 512;
        int row = (c < 16) ? (m0 + c * 16 + l16) : (n0 + (c - 16) * 16 + l16);
        const f16* base = (c < 16) ? h16 : W;
        gsrc[u] = base + (size_t)row * 768 + quad * 8;
    }

    f32x4 acc[4][4] = {};
    auto stage = [&](int k0, int buf) {
        #pragma unroll
        for (int u = 0; u < 3; ++u)
            gl_lds16(gsrc[u] + k0, &S[buf][ldst[u]]);
    };
    auto compute = [&](int buf) {
        f16x8 af[4], bg[4];
        #pragma unroll
        for (int i = 0; i < 4; ++i) {
            af[i] = *(const f16x8*)&S[buf][(wm / 16 + i) * 512 + quad * 128 + l16 * 8];
            bg[i] = *(const f16x8*)&S[buf][(16 + wn / 16 + i) * 512 + quad * 128 + l16 * 8];
        }
        #pragma unroll
        for (int i = 0; i < 4; ++i)
            #pragma unroll
            for (int jj = 0; jj < 4; ++jj)
                acc[i][jj] = MFMA_F16(af[i], bg[jj], acc[i][jj]);
    };

    stage(0, 0);
    int cur = 0;
    for (int k0 = 32; k0 < 768; k0 += 32) {
        __syncthreads();          // publishes buf[cur]; prior buf free
        stage(k0, cur ^ 1);       // flies during compute
        compute(cur);
        cur ^= 1;
    }
    __syncthreads();
    compute(cur);

    if (z < 2) {
        f16* out = z ? k16 : q16;
        #pragma unroll
        for (int jj = 0; jj < 4; ++jj) {
            int col = n0 + wn + jj * 16 + l16;
            float bb = bias[col];
            #pragma unroll
            for (int i = 0; i < 4; ++i)
                #pragma unroll
                for (int r = 0; r < 4; ++r) {
                    int row = m0 + wm + i * 16 + quad * 4 + r;  // D: col=lane&15, row=quad*4+reg
                    out[(size_t)row * 768 + col] = (f16)(acc[i][jj][r] + bb);
                }
        }
    } else {
        // v^T[b,e,s] via LDS transpose, two 128-s halves (Tb = 128e x 136)
        const int bofs = (m0 >> 10) * 768;
        #pragma unroll
        for (int h = 0; h < 2; ++h) {
            __syncthreads();                  // S / Tb region free
            if ((wm >> 7) == h) {             // waves owning s-rows of this half
                int wml = wm & 127;
                #pragma unroll
                for (int jj = 0; jj < 4; ++jj) {
                    int el = wn + jj * 16 + l16;
                    float bb = bias[n0 + el];
                    #pragma unroll
                    for (int i = 0; i < 4; ++i)
                        #pragma unroll
                        for (int r = 0; r < 4; ++r) {
                            int sl = wml + i * 16 + quad * 4 + r;
                            Tb[el * LDT + sl] = (__bf16)(acc[i][jj][r] + bb);
                        }
                }
            }
            __syncthreads();
            const int s0 = (m0 & 1023) + h * 128;
            const int ch = (t & 15) * 8;
            const int rbase = t >> 4;         // 0..31
            #pragma unroll
            for (int p = 0; p < 4; ++p) {
                int r2 = rbase + p * 32;      // e-row 0..127
                bfx8 val = *(const bfx8*)&Tb[r2 * LDT + ch];
                *(bfx8*)&vT[(size_t)(bofs + n0 + r2) * 1024 + s0 + ch] = val;
            }
        }
    }
}

// ---------------- K2: p_u = exp(q@k^T + mask), bf16; fp32 rowsum partials ---
__global__ __launch_bounds__(256) void logits_kernel(
    const f16* __restrict__ q16, const f16* __restrict__ k16,
    const float* __restrict__ amask, __bf16* __restrict__ pu, float* __restrict__ psum)
{
    const int b = blockIdx.z, nt = blockIdx.x;
    const int m0 = blockIdx.y * 128, n0 = nt * 128;
    const int t = threadIdx.x;
    const size_t pb = (size_t)b << 20;

    if (n0 > m0) {  // fully masked tile: p = 0 exactly
        int r = t >> 1, half = t & 1;
        bfx8 zv;
        #pragma unroll
        for (int e = 0; e < 8; ++e) zv[e] = (__bf16)0.f;
        #pragma unroll
        for (int c = 0; c < 8; ++c)
            *(bfx8*)&pu[pb + (size_t)(m0 + r) * 1024 + n0 + half * 64 + c * 8] = zv;
        if (t < 128) psum[((size_t)b * 1024 + m0 + t) * 8 + nt] = 0.f;
        return;
    }

    __shared__ alignas(16) char smem[32768];
    f16 (*As)[4096] = (f16(*)[4096])smem;
    f16 (*Bs)[4096] = (f16(*)[4096])(smem + 16384);
    __shared__ float rs[2][128];

    const int lane = t & 63, wave = t >> 6;
    const int wm = (wave & 1) * 64, wn = (wave >> 1) * 64;
    const int quad = lane >> 4, l16 = lane & 15;
    const size_t qb = (size_t)b * 1024 * 768;
    const int c0 = wave * 2, c1 = c0 + 1;
    const f16* ga0 = &q16[qb + (size_t)(m0 + c0 * 16 + l16) * 768 + quad * 8];
    const f16* ga1 = &q16[qb + (size_t)(m0 + c1 * 16 + l16) * 768 + quad * 8];
    const f16* gb0 = &k16[qb + (size_t)(n0 + c0 * 16 + l16) * 768 + quad * 8];
    const f16* gb1 = &k16[qb + (size_t)(n0 + c1 * 16 + l16) * 768 + quad * 8];

    f32x4 acc[4][4] = {};
    auto stage = [&](int k0, int buf) {
        gl_lds16(ga0 + k0, &As[buf][c0 * 512]);
        gl_lds16(ga1 + k0, &As[buf][c1 * 512]);
        gl_lds16(gb0 + k0, &Bs[buf][c0 * 512]);
        gl_lds16(gb1 + k0, &Bs[buf][c1 * 512]);
    };
    auto compute = [&](int buf) {
        f16x8 af[4], bg[4];
        #pragma unroll
        for (int i = 0; i < 4; ++i) {
            af[i] = *(const f16x8*)&As[buf][(wm / 16 + i) * 512 + quad * 128 + l16 * 8];
            bg[i] = *(const f16x8*)&Bs[buf][(wn / 16 + i) * 512 + quad * 128 + l16 * 8];
        }
        #pragma unroll
        for (int i = 0; i < 4; ++i)
            #pragma unroll
            for (int jj = 0; jj < 4; ++jj)
                acc[i][jj] = MFMA_F16(af[i], bg[jj], acc[i][jj]);
    };

    stage(0, 0);
    int cur = 0;
    for (int k0 = 32; k0 < 768; k0 += 32) {
        __syncthreads();
        stage(k0, cur ^ 1);
        compute(cur);
        cur ^= 1;
    }
    __syncthreads();
    compute(cur);

    float rp[4][4] = {};
    #pragma unroll
    for (int jj = 0; jj < 4; ++jj) {
        int col = n0 + wn + jj * 16 + l16;
        float am = (1.0f - amask[b * 1024 + col]) * -10000.0f;
        #pragma unroll
        for (int i = 0; i < 4; ++i)
            #pragma unroll
            for (int r = 0; r < 4; ++r) {
                int row = m0 + wm + i * 16 + quad * 4 + r;
                float s = acc[i][jj][r] + am;
                float pval = (col <= row) ? __expf(fminf(s, 80.0f)) : 0.0f;
                pu[pb + (size_t)row * 1024 + col] = (__bf16)pval;
                rp[i][r] += pval;
            }
    }
    #pragma unroll
    for (int i = 0; i < 4; ++i)
        #pragma unroll
        for (int r = 0; r < 4; ++r) {
            float v = rp[i][r];
            v += __shfl_xor(v, 1, 64);
            v += __shfl_xor(v, 2, 64);
            v += __shfl_xor(v, 4, 64);
            v += __shfl_xor(v, 8, 64);
            if (l16 == 0) rs[wn >> 6][wm + i * 16 + quad * 4 + r] = v;
        }
    __syncthreads();
    if (t < 128)
        psum[((size_t)b * 1024 + m0 + t) * 8 + nt] = rs[0][t] + rs[1][t];
}

// ---------------- K3: h = (p_u @ v) / rowsum, bf16 --------------------------
__global__ __launch_bounds__(256) void pv_kernel(
    const __bf16* __restrict__ pu, const __bf16* __restrict__ vT,
    const float* __restrict__ psum, __bf16* __restrict__ h)
{
    const int b = blockIdx.z;
    const int m0 = blockIdx.y * 128, n0 = blockIdx.x * 128;
    const int t = threadIdx.x, lane = t & 63, wave = t >> 6;
    const int wm = (wave & 1) * 64, wn = (wave >> 1) * 64;
    const int quad = lane >> 4, l16 = lane & 15;
    const size_t pb = (size_t)b << 20;
    const size_t vb = (size_t)b * 768 * 1024;

    __shared__ alignas(16) char smem[32768];
    __bf16 (*As)[4096] = (__bf16(*)[4096])smem;
    __bf16 (*Bs)[4096] = (__bf16(*)[4096])(smem + 16384);
    __shared__ float invl[128];

    if (t < 128) {
        const float* pr = &psum[((size_t)b * 1024 + m0 + t) * 8];
        f32x4 a = *(const f32x4*)pr, c = *(const f32x4*)(pr + 4);
        invl[t] = 1.0f / (a[0] + a[1] + a[2] + a[3] + c[0] + c[1] + c[2] + c[3]);
    }

    const int c0 = wave * 2, c1 = c0 + 1;
    const __bf16* ga0 = &pu[pb + (size_t)(m0 + c0 * 16 + l16) * 1024 + quad * 8];
    const __bf16* ga1 = &pu[pb + (size_t)(m0 + c1 * 16 + l16) * 1024 + quad * 8];
    const __bf16* gb0 = &vT[vb + (size_t)(n0 + c0 * 16 + l16) * 1024 + quad * 8];
    const __bf16* gb1 = &vT[vb + (size_t)(n0 + c1 * 16 + l16) * 1024 + quad * 8];

    f32x4 acc[4][4] = {};
    auto stage = [&](int k0, int buf) {
        gl_lds16(ga0 + k0, &As[buf][c0 * 512]);
        gl_lds16(ga1 + k0, &As[buf][c1 * 512]);
        gl_lds16(gb0 + k0, &Bs[buf][c0 * 512]);
        gl_lds16(gb1 + k0, &Bs[buf][c1 * 512]);
    };
    auto compute = [&](int buf) {
        bfx8 af[4], bg[4];
        #pragma unroll
        for (int i = 0; i < 4; ++i) {
            af[i] = *(const bfx8*)&As[buf][(wm / 16 + i) * 512 + quad * 128 + l16 * 8];
            bg[i] = *(const bfx8*)&Bs[buf][(wn / 16 + i) * 512 + quad * 128 + l16 * 8];
        }
        #pragma unroll
        for (int i = 0; i < 4; ++i)
            #pragma unroll
            for (int jj = 0; jj < 4; ++jj)
                acc[i][jj] = MFMA_BF16(af[i], bg[jj], acc[i][jj]);
    };

    const int kend = m0 + 128;  // p_u is exactly 0 above the diagonal
    stage(0, 0);
    int cur = 0;
    for (int k0 = 32; k0 < kend; k0 += 32) {
        __syncthreads();
        stage(k0, cur ^ 1);
        compute(cur);
        cur ^= 1;
    }
    __syncthreads();
    compute(cur);

    #pragma unroll
    for (int jj = 0; jj < 4; ++jj) {
        int col = n0 + wn + jj * 16 + l16;
        #pragma unroll
        for (int i = 0; i < 4; ++i)
            #pragma unroll
            for (int r = 0; r < 4; ++r) {
                int rl = wm + i * 16 + quad * 4 + r;
                h[((size_t)b * 1024 + m0 + rl) * 768 + col] = (__bf16)(acc[i][jj][r] * invl[rl]);
            }
    }
}

// ---------------- K4: out = relu(h @ W1^T + b1) @ W2^T + b2 -----------------
__global__ __launch_bounds__(256) void mlp_kernel(
    const __bf16* __restrict__ h, const float* __restrict__ W1, const float* __restrict__ b1,
    const float* __restrict__ W2, const float* __restrict__ b2, float* __restrict__ out)
{
    const int wave = threadIdx.x >> 6, lane = threadIdx.x & 63;
    const int quad = lane >> 4, l16 = lane & 15;
    const int m0 = blockIdx.x * 64 + wave * 16;

    f32x4 acc[4] = {};
    for (int k0 = 0; k0 < 768; k0 += 32) {
        bfx8 af = *(const bfx8*)&h[(size_t)(m0 + l16) * 768 + k0 + quad * 8];
        #pragma unroll
        for (int jj = 0; jj < 4; ++jj) {
            const float* wp = W1 + (size_t)(jj * 16 + l16) * 768 + k0 + quad * 8;
            f32x4 w0 = *(const f32x4*)wp;
            f32x4 w1 = *(const f32x4*)(wp + 4);
            bfx8 bg;
            #pragma unroll
            for (int e = 0; e < 4; ++e) { bg[e] = (__bf16)w0[e]; bg[e + 4] = (__bf16)w1[e]; }
            acc[jj] = MFMA_BF16(af, bg, acc[jj]);
        }
    }
    float part[4][2] = {};
    #pragma unroll
    for (int jj = 0; jj < 4; ++jj) {
        int c = jj * 16 + l16;
        float bb = b1[c];
        float w20 = W2[c], w21 = W2[64 + c];
        #pragma unroll
        for (int r = 0; r < 4; ++r) {
            float x = fmaxf(acc[jj][r] + bb, 0.f);
            part[r][0] += x * w20;
            part[r][1] += x * w21;
        }
    }
    #pragma unroll
    for (int off = 1; off < 16; off <<= 1)
        #pragma unroll
        for (int r = 0; r < 4; ++r) {
            part[r][0] += __shfl_xor(part[r][0], off, 64);
            part[r][1] += __shfl_xor(part[r][1], off, 64);
        }
    if (l16 == 0) {
        #pragma unroll
        for (int r = 0; r < 4; ++r) {
            int row = m0 + quad * 4 + r;
            out[(size_t)row * 2 + 0] = part[r][0] + b2[0];
            out[(size_t)row * 2 + 1] = part[r][1] + b2[1];
        }
    }
}

// ---------------------------------------------------------------------------
extern "C" void kernel_launch(void* const* d_in, const int* in_sizes, int n_in,
                              void* d_out, int out_size, void* d_ws, size_t ws_size,
                              hipStream_t stream)
{
    const float* hidden = (const float*)d_in[0];
    const float* amask  = (const float*)d_in[1];
    const float* Wk = (const float*)d_in[2];
    const float* bk = (const float*)d_in[3];
    const float* Wq = (const float*)d_in[4];
    const float* bq = (const float*)d_in[5];
    const float* Wv = (const float*)d_in[6];
    const float* bv = (const float*)d_in[7];
    const float* W1 = (const float*)d_in[8];
    const float* b1 = (const float*)d_in[9];
    const float* W2 = (const float*)d_in[10];
    const float* b2 = (const float*)d_in[11];
    float* out = (float*)d_out;

    char* ws = (char*)d_ws;
    const size_t MB = 1024 * 1024;
    // Phase 1 (qkv): h16 @0 (48MB), w16 @48MB (3.4MB)  [dead after qkv]
    // Phase 2 (logits): pu @0 (64MB, aliases phase1), psum @64MB (1MB)
    // q16 @66MB (48), k16 @114MB (48), vT @162MB (48)
    // Phase 3 (pv/mlp): h @66MB (aliases q16, dead after logits)
    f16* h16 = (f16*)ws;
    f16* wq16 = (f16*)(ws + 48 * MB);
    f16* wk16 = wq16 + 589824;
    f16* wv16 = wk16 + 589824;
    __bf16* pu  = (__bf16*)ws;
    float*  psum = (float*)(ws + 64 * MB);
    f16* q16 = (f16*)(ws + 66 * MB);
    f16* k16 = (f16*)(ws + 114 * MB);
    __bf16* vT = (__bf16*)(ws + 162 * MB);
    __bf16* h  = (__bf16*)(ws + 66 * MB);
    const size_t NEED = 210 * MB;
    if (ws_size < NEED) {
        fprintf(stderr, "[Attn kernel] ws too small: %zu < %zu — skipping launches\n",
                ws_size, NEED);
        return;
    }

    cvt_f32_f16<<<24576, 256, 0, stream>>>(hidden, h16, 25165824);
    cvt3_w<<<dim3(576, 3), 256, 0, stream>>>(Wq, Wk, Wv, wq16, wk16, wv16);

    qkv_kernel<<<2304, 512, 0, stream>>>(
        h16, wq16, wk16, wv16, bq, bk, bv, q16, k16, vT);
    logits_kernel<<<dim3(8, 8, 32), 256, 0, stream>>>(q16, k16, amask, pu, psum);
    pv_kernel<<<dim3(6, 8, 32), 256, 0, stream>>>(pu, vT, psum, h);
    mlp_kernel<<<512, 256, 0, stream>>>(h, W1, b1, W2, b2, out);
}

// Round 7
// 556.743 us; speedup vs baseline: 1.3333x; 1.1128x over previous
//
#include <hip/hip_runtime.h>
#include <hip/hip_bf16.h>
#include <cstdio>

// ---------------------------------------------------------------------------
// Attn_59940563583594: hidden[32,1024,768] -> QKV -> causal attn (no 1/sqrt(d))
//                      -> relu MLP(768->64) -> out[32,1024,2] fp32
// Numerics (verified R2-R6: absmax 9.8e-4 vs 3.8e-3 threshold):
//   f16 storage/MFMA for hidden/W/q/k, no-max softmax (exp clamp 80,
//   unnormalized bf16 p, fp32 row sums, normalize in PV), bf16 PV + MLP.
// R7: apply the R6 qkv recipe (256x128 tile, 512 thr, XCD affinity) to
//   logits and pv; triangular launch for logits (20 causal tiles/batch,
//   no zero-fill blocks); batch->XCD affinity so q/k (3MB) and pu/vT
//   (3.5MB) stay L2-resident. pv masks unwritten psum entries per-row.
// ---------------------------------------------------------------------------

typedef _Float16 f16;
typedef f16    f16x8 __attribute__((ext_vector_type(8)));
typedef f16    f16x4 __attribute__((ext_vector_type(4)));
typedef __bf16 bfx8  __attribute__((ext_vector_type(8)));
typedef float  f32x4 __attribute__((ext_vector_type(4)));

#define MFMA_F16(a,b,c)  __builtin_amdgcn_mfma_f32_16x16x32_f16((a),(b),(c),0,0,0)
#define MFMA_BF16(a,b,c) __builtin_amdgcn_mfma_f32_16x16x32_bf16((a),(b),(c),0,0,0)

static constexpr int LDT = 136;  // v-transpose buffer stride (bf16)

__device__ __forceinline__ void gl_lds16(const void* g, void* l) {
    __builtin_amdgcn_global_load_lds(
        (const __attribute__((address_space(1))) void*)g,
        (__attribute__((address_space(3))) void*)l, 16, 0, 0);
}

// ---------------- fp32 -> f16 converts --------------------------------------
__global__ __launch_bounds__(256) void cvt_f32_f16(
    const float* __restrict__ x, f16* __restrict__ y, int n)
{
    int base = (blockIdx.x * 256 + threadIdx.x) * 4;
    if (base >= n) return;
    f32x4 v = *(const f32x4*)(x + base);
    f16x4 o;
    #pragma unroll
    for (int e = 0; e < 4; ++e) o[e] = (f16)v[e];
    *(f16x4*)(y + base) = o;
}

__global__ __launch_bounds__(256) void cvt3_w(
    const float* __restrict__ Wq, const float* __restrict__ Wk, const float* __restrict__ Wv,
    f16* __restrict__ oq, f16* __restrict__ ok, f16* __restrict__ ov)
{
    const int z = blockIdx.y;
    const float* s = (z == 0) ? Wq : (z == 1) ? Wk : Wv;
    f16* d = (z == 0) ? oq : (z == 1) ? ok : ov;
    int base = (blockIdx.x * 256 + threadIdx.x) * 4;
    f32x4 v = *(const f32x4*)(s + base);
    f16x4 o;
    #pragma unroll
    for (int e = 0; e < 4; ++e) o[e] = (f16)v[e];
    *(f16x4*)(d + base) = o;
}

// ---------------- K1: fused q,k,v projections, 256x128 tiles (R6) -----------
__global__ __launch_bounds__(512, 4) void qkv_kernel(
    const f16* __restrict__ h16,
    const f16* __restrict__ wq, const f16* __restrict__ wk, const f16* __restrict__ wv,
    const float* __restrict__ bq, const float* __restrict__ bk, const float* __restrict__ bv,
    f16* __restrict__ q16, f16* __restrict__ k16, __bf16* __restrict__ vT)
{
    const int f = blockIdx.x;
    const int xcd = f & 7;
    const int j = f >> 3;
    const int nt = j % 6;
    const int z  = (j / 6) % 3;
    const int mi = j / 18;
    const int mt = xcd + 8 * mi;
    const int m0 = mt * 256, n0 = nt * 128;

    const f16* W = (z == 0) ? wq : (z == 1) ? wk : wv;
    const float* bias = (z == 0) ? bq : (z == 1) ? bk : bv;

    __shared__ alignas(16) f16 S[2][24 * 512];          // 48 KB
    __bf16* Tb = (__bf16*)&S[0][0];                     // aliased, z==2 epilogue

    const int t = threadIdx.x, lane = t & 63, wave = t >> 6;
    const int wm = (wave & 3) * 64, wn = (wave >> 2) * 64;
    const int quad = lane >> 4, l16 = lane & 15;

    const f16* gsrc[3];
    int ldst[3];
    #pragma unroll
    for (int u = 0; u < 3; ++u) {
        int c = wave * 3 + u;
        ldst[u] = c * 512;
        int row = (c < 16) ? (m0 + c * 16 + l16) : (n0 + (c - 16) * 16 + l16);
        const f16* base = (c < 16) ? h16 : W;
        gsrc[u] = base + (size_t)row * 768 + quad * 8;
    }

    f32x4 acc[4][4] = {};
    auto stage = [&](int k0, int buf) {
        #pragma unroll
        for (int u = 0; u < 3; ++u)
            gl_lds16(gsrc[u] + k0, &S[buf][ldst[u]]);
    };
    auto compute = [&](int buf) {
        f16x8 af[4], bg[4];
        #pragma unroll
        for (int i = 0; i < 4; ++i) {
            af[i] = *(const f16x8*)&S[buf][(wm / 16 + i) * 512 + quad * 128 + l16 * 8];
            bg[i] = *(const f16x8*)&S[buf][(16 + wn / 16 + i) * 512 + quad * 128 + l16 * 8];
        }
        #pragma unroll
        for (int i = 0; i < 4; ++i)
            #pragma unroll
            for (int jj = 0; jj < 4; ++jj)
                acc[i][jj] = MFMA_F16(af[i], bg[jj], acc[i][jj]);
    };

    stage(0, 0);
    int cur = 0;
    for (int k0 = 32; k0 < 768; k0 += 32) {
        __syncthreads();
        stage(k0, cur ^ 1);
        compute(cur);
        cur ^= 1;
    }
    __syncthreads();
    compute(cur);

    if (z < 2) {
        f16* out = z ? k16 : q16;
        #pragma unroll
        for (int jj = 0; jj < 4; ++jj) {
            int col = n0 + wn + jj * 16 + l16;
            float bb = bias[col];
            #pragma unroll
            for (int i = 0; i < 4; ++i)
                #pragma unroll
                for (int r = 0; r < 4; ++r) {
                    int row = m0 + wm + i * 16 + quad * 4 + r;  // D: col=lane&15, row=quad*4+reg
                    out[(size_t)row * 768 + col] = (f16)(acc[i][jj][r] + bb);
                }
        }
    } else {
        const int bofs = (m0 >> 10) * 768;
        #pragma unroll
        for (int h = 0; h < 2; ++h) {
            __syncthreads();
            if ((wm >> 7) == h) {
                int wml = wm & 127;
                #pragma unroll
                for (int jj = 0; jj < 4; ++jj) {
                    int el = wn + jj * 16 + l16;
                    float bb = bias[n0 + el];
                    #pragma unroll
                    for (int i = 0; i < 4; ++i)
                        #pragma unroll
                        for (int r = 0; r < 4; ++r) {
                            int sl = wml + i * 16 + quad * 4 + r;
                            Tb[el * LDT + sl] = (__bf16)(acc[i][jj][r] + bb);
                        }
                }
            }
            __syncthreads();
            const int s0 = (m0 & 1023) + h * 128;
            const int ch = (t & 15) * 8;
            const int rbase = t >> 4;
            #pragma unroll
            for (int p = 0; p < 4; ++p) {
                int r2 = rbase + p * 32;
                bfx8 val = *(const bfx8*)&Tb[r2 * LDT + ch];
                *(bfx8*)&vT[(size_t)(bofs + n0 + r2) * 1024 + s0 + ch] = val;
            }
        }
    }
}

// ---------------- K2: p_u = exp(q@k^T + mask), 256x128 causal tiles ---------
// grid 640 = 8 xcd * (4 batch-groups * 20 causal tiles). batch = xcd+8*(j/20).
__global__ __launch_bounds__(512, 4) void logits_kernel(
    const f16* __restrict__ q16, const f16* __restrict__ k16,
    const float* __restrict__ amask, __bf16* __restrict__ pu, float* __restrict__ psum)
{
    const int f = blockIdx.x;
    const int xcd = f & 7;
    const int j = f >> 3;
    const int b = xcd + 8 * (j / 20);
    const int tile = j % 20;
    const int mt = (tile < 2) ? 0 : (tile < 6) ? 1 : (tile < 12) ? 2 : 3;
    const int nt = tile - ((mt == 0) ? 0 : (mt == 1) ? 2 : (mt == 2) ? 6 : 12);
    const int m0 = mt * 256, n0 = nt * 128;
    const size_t pb = (size_t)b << 20;
    const size_t qb = (size_t)b * 1024 * 768;

    __shared__ alignas(16) f16 S[2][24 * 512];   // 48 KB dbuf
    __shared__ float rs[2][256];

    const int t = threadIdx.x, lane = t & 63, wave = t >> 6;
    const int wm = (wave & 3) * 64, wn = (wave >> 2) * 64;
    const int quad = lane >> 4, l16 = lane & 15;

    const f16* gsrc[3];
    int ldst[3];
    #pragma unroll
    for (int u = 0; u < 3; ++u) {
        int c = wave * 3 + u;
        ldst[u] = c * 512;
        const f16* base = (c < 16) ? (q16 + qb + (size_t)(m0 + c * 16 + l16) * 768)
                                   : (k16 + qb + (size_t)(n0 + (c - 16) * 16 + l16) * 768);
        gsrc[u] = base + quad * 8;
    }

    f32x4 acc[4][4] = {};
    auto stage = [&](int k0, int buf) {
        #pragma unroll
        for (int u = 0; u < 3; ++u)
            gl_lds16(gsrc[u] + k0, &S[buf][ldst[u]]);
    };
    auto compute = [&](int buf) {
        f16x8 af[4], bg[4];
        #pragma unroll
        for (int i = 0; i < 4; ++i) {
            af[i] = *(const f16x8*)&S[buf][(wm / 16 + i) * 512 + quad * 128 + l16 * 8];
            bg[i] = *(const f16x8*)&S[buf][(16 + wn / 16 + i) * 512 + quad * 128 + l16 * 8];
        }
        #pragma unroll
        for (int i = 0; i < 4; ++i)
            #pragma unroll
            for (int jj = 0; jj < 4; ++jj)
                acc[i][jj] = MFMA_F16(af[i], bg[jj], acc[i][jj]);
    };

    stage(0, 0);
    int cur = 0;
    for (int k0 = 32; k0 < 768; k0 += 32) {
        __syncthreads();
        stage(k0, cur ^ 1);
        compute(cur);
        cur ^= 1;
    }
    __syncthreads();
    compute(cur);

    float rp[4][4] = {};
    #pragma unroll
    for (int jj = 0; jj < 4; ++jj) {
        int col = n0 + wn + jj * 16 + l16;
        float am = (1.0f - amask[b * 1024 + col]) * -10000.0f;
        #pragma unroll
        for (int i = 0; i < 4; ++i)
            #pragma unroll
            for (int r = 0; r < 4; ++r) {
                int row = m0 + wm + i * 16 + quad * 4 + r;
                float s = acc[i][jj][r] + am;
                float pval = (col <= row) ? __expf(fminf(s, 80.0f)) : 0.0f;
                pu[pb + (size_t)row * 1024 + col] = (__bf16)pval;
                rp[i][r] += pval;
            }
    }
    #pragma unroll
    for (int i = 0; i < 4; ++i)
        #pragma unroll
        for (int r = 0; r < 4; ++r) {
            float v = rp[i][r];
            v += __shfl_xor(v, 1, 64);
            v += __shfl_xor(v, 2, 64);
            v += __shfl_xor(v, 4, 64);
            v += __shfl_xor(v, 8, 64);
            if (l16 == 0) rs[wn >> 6][wm + i * 16 + quad * 4 + r] = v;
        }
    __syncthreads();
    if (t < 256)
        psum[((size_t)b * 1024 + m0 + t) * 8 + nt] = rs[0][t] + rs[1][t];
}

// ---------------- K3: h = (p_u @ v) / rowsum, 256x128 tiles -----------------
// grid 768 = 8 xcd * (4 batch-groups * 24 tiles). batch = xcd+8*(j/24).
__global__ __launch_bounds__(512, 4) void pv_kernel(
    const __bf16* __restrict__ pu, const __bf16* __restrict__ vT,
    const float* __restrict__ psum, __bf16* __restrict__ h)
{
    const int f = blockIdx.x;
    const int xcd = f & 7;
    const int j = f >> 3;
    const int b = xcd + 8 * (j / 24);
    const int tile = j % 24;
    const int mt = tile / 6, nt = tile % 6;
    const int m0 = mt * 256, n0 = nt * 128;
    const size_t pb = (size_t)b << 20;
    const size_t vb = (size_t)b * 768 * 1024;

    __shared__ alignas(16) __bf16 S[2][24 * 512];   // 48 KB dbuf
    __shared__ float invl[256];

    const int t = threadIdx.x, lane = t & 63, wave = t >> 6;
    const int wm = (wave & 3) * 64, wn = (wave >> 2) * 64;
    const int quad = lane >> 4, l16 = lane & 15;

    if (t < 256) {
        int row = m0 + t;
        int lim = row >> 7;  // psum[row][nt] valid/written only for nt <= row>>7
        const float* pr = &psum[((size_t)b * 1024 + row) * 8];
        float s = 0.f;
        #pragma unroll
        for (int n = 0; n < 8; ++n) s += (n <= lim) ? pr[n] : 0.f;
        invl[t] = 1.0f / s;
    }

    const __bf16* gsrc[3];
    int ldst[3];
    #pragma unroll
    for (int u = 0; u < 3; ++u) {
        int c = wave * 3 + u;
        ldst[u] = c * 512;
        const __bf16* base = (c < 16) ? (pu + pb + (size_t)(m0 + c * 16 + l16) * 1024)
                                      : (vT + vb + (size_t)(n0 + (c - 16) * 16 + l16) * 1024);
        gsrc[u] = base + quad * 8;
    }

    f32x4 acc[4][4] = {};
    auto stage = [&](int k0, int buf) {
        #pragma unroll
        for (int u = 0; u < 3; ++u)
            gl_lds16(gsrc[u] + k0, &S[buf][ldst[u]]);
    };
    auto compute = [&](int buf) {
        bfx8 af[4], bg[4];
        #pragma unroll
        for (int i = 0; i < 4; ++i) {
            af[i] = *(const bfx8*)&S[buf][(wm / 16 + i) * 512 + quad * 128 + l16 * 8];
            bg[i] = *(const bfx8*)&S[buf][(16 + wn / 16 + i) * 512 + quad * 128 + l16 * 8];
        }
        #pragma unroll
        for (int i = 0; i < 4; ++i)
            #pragma unroll
            for (int jj = 0; jj < 4; ++jj)
                acc[i][jj] = MFMA_BF16(af[i], bg[jj], acc[i][jj]);
    };

    const int kend = m0 + 256;  // p_u is exactly 0 above the diagonal
    stage(0, 0);
    int cur = 0;
    for (int k0 = 32; k0 < kend; k0 += 32) {
        __syncthreads();
        stage(k0, cur ^ 1);
        compute(cur);
        cur ^= 1;
    }
    __syncthreads();
    compute(cur);

    #pragma unroll
    for (int jj = 0; jj < 4; ++jj) {
        int col = n0 + wn + jj * 16 + l16;
        #pragma unroll
        for (int i = 0; i < 4; ++i)
            #pragma unroll
            for (int r = 0; r < 4; ++r) {
                int rl = wm + i * 16 + quad * 4 + r;
                h[((size_t)b * 1024 + m0 + rl) * 768 + col] = (__bf16)(acc[i][jj][r] * invl[rl]);
            }
    }
}

// ---------------- K4: out = relu(h @ W1^T + b1) @ W2^T + b2 -----------------
__global__ __launch_bounds__(256) void mlp_kernel(
    const __bf16* __restrict__ h, const float* __restrict__ W1, const float* __restrict__ b1,
    const float* __restrict__ W2, const float* __restrict__ b2, float* __restrict__ out)
{
    const int wave = threadIdx.x >> 6, lane = threadIdx.x & 63;
    const int quad = lane >> 4, l16 = lane & 15;
    const int m0 = blockIdx.x * 64 + wave * 16;

    f32x4 acc[4] = {};
    for (int k0 = 0; k0 < 768; k0 += 32) {
        bfx8 af = *(const bfx8*)&h[(size_t)(m0 + l16) * 768 + k0 + quad * 8];
        #pragma unroll
        for (int jj = 0; jj < 4; ++jj) {
            const float* wp = W1 + (size_t)(jj * 16 + l16) * 768 + k0 + quad * 8;
            f32x4 w0 = *(const f32x4*)wp;
            f32x4 w1 = *(const f32x4*)(wp + 4);
            bfx8 bg;
            #pragma unroll
            for (int e = 0; e < 4; ++e) { bg[e] = (__bf16)w0[e]; bg[e + 4] = (__bf16)w1[e]; }
            acc[jj] = MFMA_BF16(af, bg, acc[jj]);
        }
    }
    float part[4][2] = {};
    #pragma unroll
    for (int jj = 0; jj < 4; ++jj) {
        int c = jj * 16 + l16;
        float bb = b1[c];
        float w20 = W2[c], w21 = W2[64 + c];
        #pragma unroll
        for (int r = 0; r < 4; ++r) {
            float x = fmaxf(acc[jj][r] + bb, 0.f);
            part[r][0] += x * w20;
            part[r][1] += x * w21;
        }
    }
    #pragma unroll
    for (int off = 1; off < 16; off <<= 1)
        #pragma unroll
        for (int r = 0; r < 4; ++r) {
            part[r][0] += __shfl_xor(part[r][0], off, 64);
            part[r][1] += __shfl_xor(part[r][1], off, 64);
        }
    if (l16 == 0) {
        #pragma unroll
        for (int r = 0; r < 4; ++r) {
            int row = m0 + quad * 4 + r;
            out[(size_t)row * 2 + 0] = part[r][0] + b2[0];
            out[(size_t)row * 2 + 1] = part[r][1] + b2[1];
        }
    }
}

// ---------------------------------------------------------------------------
extern "C" void kernel_launch(void* const* d_in, const int* in_sizes, int n_in,
                              void* d_out, int out_size, void* d_ws, size_t ws_size,
                              hipStream_t stream)
{
    const float* hidden = (const float*)d_in[0];
    const float* amask  = (const float*)d_in[1];
    const float* Wk = (const float*)d_in[2];
    const float* bk = (const float*)d_in[3];
    const float* Wq = (const float*)d_in[4];
    const float* bq = (const float*)d_in[5];
    const float* Wv = (const float*)d_in[6];
    const float* bv = (const float*)d_in[7];
    const float* W1 = (const float*)d_in[8];
    const float* b1 = (const float*)d_in[9];
    const float* W2 = (const float*)d_in[10];
    const float* b2 = (const float*)d_in[11];
    float* out = (float*)d_out;

    char* ws = (char*)d_ws;
    const size_t MB = 1024 * 1024;
    f16* h16 = (f16*)ws;
    f16* wq16 = (f16*)(ws + 48 * MB);
    f16* wk16 = wq16 + 589824;
    f16* wv16 = wk16 + 589824;
    __bf16* pu  = (__bf16*)ws;                 // aliases h16/W16 (dead after qkv)
    float*  psum = (float*)(ws + 64 * MB);
    f16* q16 = (f16*)(ws + 66 * MB);
    f16* k16 = (f16*)(ws + 114 * MB);
    __bf16* vT = (__bf16*)(ws + 162 * MB);
    __bf16* h  = (__bf16*)(ws + 66 * MB);      // aliases q16 (dead after logits)
    const size_t NEED = 210 * MB;
    if (ws_size < NEED) {
        fprintf(stderr, "[Attn kernel] ws too small: %zu < %zu — skipping launches\n",
                ws_size, NEED);
        return;
    }

    cvt_f32_f16<<<24576, 256, 0, stream>>>(hidden, h16, 25165824);
    cvt3_w<<<dim3(576, 3), 256, 0, stream>>>(Wq, Wk, Wv, wq16, wk16, wv16);

    qkv_kernel<<<2304, 512, 0, stream>>>(
        h16, wq16, wk16, wv16, bq, bk, bv, q16, k16, vT);
    logits_kernel<<<640, 512, 0, stream>>>(q16, k16, amask, pu, psum);
    pv_kernel<<<768, 512, 0, stream>>>(pu, vT, psum, h);
    mlp_kernel<<<512, 256, 0, stream>>>(h, W1, b1, W2, b2, out);
}

// Round 8
// 548.592 us; speedup vs baseline: 1.3532x; 1.0149x over previous
//
#include <hip/hip_runtime.h>
#include <hip/hip_bf16.h>
#include <cstdio>

// ---------------------------------------------------------------------------
// Attn_59940563583594: hidden[32,1024,768] -> QKV -> causal attn (no 1/sqrt(d))
//                      -> relu MLP(768->64) -> out[32,1024,2] fp32
// Numerics (verified R2-R7: absmax 9.8e-4 vs 3.8e-3 threshold):
//   f16 storage/MFMA for hidden/W/q/k, no-max softmax (exp clamp 80,
//   unnormalized bf16 p, fp32 row sums, normalize in PV), bf16 PV + MLP.
// R8: all phases move logical bytes at a pinned ~6.4 TB/s (R3..R7 evidence:
//   time tracks staged bytes, invariant to barrier structure & L2 vs HBM).
//   So: qkv -> 256x256 tiles / 1024 thr / 16 waves (wave-tile stays 64x64,
//   acc 64 VGPR), 2 gl_lds per wave per step. Staged bytes 1.33GB -> 0.88GB.
//   logits/pv unchanged as controls.
// ---------------------------------------------------------------------------

typedef _Float16 f16;
typedef f16    f16x8 __attribute__((ext_vector_type(8)));
typedef f16    f16x4 __attribute__((ext_vector_type(4)));
typedef __bf16 bfx8  __attribute__((ext_vector_type(8)));
typedef float  f32x4 __attribute__((ext_vector_type(4)));

#define MFMA_F16(a,b,c)  __builtin_amdgcn_mfma_f32_16x16x32_f16((a),(b),(c),0,0,0)
#define MFMA_BF16(a,b,c) __builtin_amdgcn_mfma_f32_16x16x32_bf16((a),(b),(c),0,0,0)

static constexpr int LDT = 136;   // v-transpose stride (logits/pv path, R7)
static constexpr int LDT2 = 264;  // qkv-256 v-transpose stride (128e x 256s)

__device__ __forceinline__ void gl_lds16(const void* g, void* l) {
    __builtin_amdgcn_global_load_lds(
        (const __attribute__((address_space(1))) void*)g,
        (__attribute__((address_space(3))) void*)l, 16, 0, 0);
}

// ---------------- fp32 -> f16 converts --------------------------------------
__global__ __launch_bounds__(256) void cvt_f32_f16(
    const float* __restrict__ x, f16* __restrict__ y, int n)
{
    int base = (blockIdx.x * 256 + threadIdx.x) * 4;
    if (base >= n) return;
    f32x4 v = *(const f32x4*)(x + base);
    f16x4 o;
    #pragma unroll
    for (int e = 0; e < 4; ++e) o[e] = (f16)v[e];
    *(f16x4*)(y + base) = o;
}

__global__ __launch_bounds__(256) void cvt3_w(
    const float* __restrict__ Wq, const float* __restrict__ Wk, const float* __restrict__ Wv,
    f16* __restrict__ oq, f16* __restrict__ ok, f16* __restrict__ ov)
{
    const int z = blockIdx.y;
    const float* s = (z == 0) ? Wq : (z == 1) ? Wk : Wv;
    f16* d = (z == 0) ? oq : (z == 1) ? ok : ov;
    int base = (blockIdx.x * 256 + threadIdx.x) * 4;
    f32x4 v = *(const f32x4*)(s + base);
    f16x4 o;
    #pragma unroll
    for (int e = 0; e < 4; ++e) o[e] = (f16)v[e];
    *(f16x4*)(d + base) = o;
}

// ---------------- K1: fused q,k,v projections, 256x256 tiles ----------------
// 1152 blocks x 1024 thr. xcd=f&7, j=f>>3: nt=j%3, z=(j/3)%3, mi=j/9,
// mt=xcd+8*mi. Per K-step: 32 KB staged (16 A + 16 B chunks), 2 gl_lds/wave.
__global__ __launch_bounds__(1024, 4) void qkv_kernel(
    const f16* __restrict__ h16,
    const f16* __restrict__ wq, const f16* __restrict__ wk, const f16* __restrict__ wv,
    const float* __restrict__ bq, const float* __restrict__ bk, const float* __restrict__ bv,
    f16* __restrict__ q16, f16* __restrict__ k16, __bf16* __restrict__ vT)
{
    const int f = blockIdx.x;
    const int xcd = f & 7;
    const int j = f >> 3;
    const int nt = j % 3;
    const int z  = (j / 3) % 3;
    const int mi = j / 9;
    const int mt = xcd + 8 * mi;
    const int m0 = mt * 256, n0 = nt * 256;

    const f16* W = (z == 0) ? wq : (z == 1) ? wk : wv;
    const float* bias = (z == 0) ? bq : (z == 1) ? bk : bv;

    // 64 KB dbuf (2 x 32 chunks x 512 f16); Tb (128 x 264 bf16 = 67.5 KB)
    // aliases it for the z==2 transpose epilogue.
    __shared__ alignas(16) char smem[67584];
    f16 (*S)[16384] = (f16 (*)[16384])smem;
    __bf16* Tb = (__bf16*)smem;

    const int t = threadIdx.x, lane = t & 63, wave = t >> 6;   // wave 0..15
    const int wm = (wave & 3) * 64, wn = (wave >> 2) * 64;
    const int quad = lane >> 4, l16 = lane & 15;

    // staging: chunk c = 16 rows x 32 cols; lane i -> (row=i&15, colchunk=i>>4)
    const f16* gsrc[2];
    int ldst[2];
    #pragma unroll
    for (int u = 0; u < 2; ++u) {
        int c = wave * 2 + u;
        ldst[u] = c * 512;
        int row = (c < 16) ? (m0 + c * 16 + l16) : (n0 + (c - 16) * 16 + l16);
        const f16* base = (c < 16) ? h16 : W;
        gsrc[u] = base + (size_t)row * 768 + quad * 8;
    }

    f32x4 acc[4][4] = {};
    auto stage = [&](int k0, int buf) {
        #pragma unroll
        for (int u = 0; u < 2; ++u)
            gl_lds16(gsrc[u] + k0, &S[buf][ldst[u]]);
    };
    auto compute = [&](int buf) {
        f16x8 af[4], bg[4];
        #pragma unroll
        for (int i = 0; i < 4; ++i) {
            af[i] = *(const f16x8*)&S[buf][(wm / 16 + i) * 512 + quad * 128 + l16 * 8];
            bg[i] = *(const f16x8*)&S[buf][(16 + wn / 16 + i) * 512 + quad * 128 + l16 * 8];
        }
        #pragma unroll
        for (int i = 0; i < 4; ++i)
            #pragma unroll
            for (int jj = 0; jj < 4; ++jj)
                acc[i][jj] = MFMA_F16(af[i], bg[jj], acc[i][jj]);
    };

    stage(0, 0);
    int cur = 0;
    for (int k0 = 32; k0 < 768; k0 += 32) {
        __syncthreads();          // publishes buf[cur]; prior buf free
        stage(k0, cur ^ 1);       // flies during compute
        compute(cur);
        cur ^= 1;
    }
    __syncthreads();
    compute(cur);

    if (z < 2) {
        f16* out = z ? k16 : q16;
        #pragma unroll
        for (int jj = 0; jj < 4; ++jj) {
            int col = n0 + wn + jj * 16 + l16;
            float bb = bias[col];
            #pragma unroll
            for (int i = 0; i < 4; ++i)
                #pragma unroll
                for (int r = 0; r < 4; ++r) {
                    int row = m0 + wm + i * 16 + quad * 4 + r;  // D: col=lane&15, row=quad*4+reg
                    out[(size_t)row * 768 + col] = (f16)(acc[i][jj][r] + bb);
                }
        }
    } else {
        // v^T[b,e,s]: 256e x 256s tile via LDS, two 128-e halves
        const int bofs = (m0 >> 10) * 768;
        const int s0 = m0 & 1023;
        #pragma unroll
        for (int half = 0; half < 2; ++half) {
            __syncthreads();                  // S / Tb region free
            if ((wn >> 7) == half) {          // waves whose e-cols are in this half
                int wnl = wn & 127;
                #pragma unroll
                for (int jj = 0; jj < 4; ++jj) {
                    int el = wnl + jj * 16 + l16;
                    float bb = bias[n0 + half * 128 + el];
                    #pragma unroll
                    for (int i = 0; i < 4; ++i)
                        #pragma unroll
                        for (int r = 0; r < 4; ++r) {
                            int sl = wm + i * 16 + quad * 4 + r;
                            Tb[el * LDT2 + sl] = (__bf16)(acc[i][jj][r] + bb);
                        }
                }
            }
            __syncthreads();
            const int ch = (t & 31) * 8;      // s-col chunk 0..248
            const int rbase = t >> 5;         // 0..31
            #pragma unroll
            for (int p = 0; p < 4; ++p) {
                int r2 = rbase + p * 32;      // e-row 0..127
                bfx8 val = *(const bfx8*)&Tb[r2 * LDT2 + ch];
                *(bfx8*)&vT[(size_t)(bofs + n0 + half * 128 + r2) * 1024 + s0 + ch] = val;
            }
        }
    }
}

// ---------------- K2: p_u = exp(q@k^T + mask), 256x128 causal tiles ---------
// grid 640 = 8 xcd * (4 batch-groups * 20 causal tiles). batch = xcd+8*(j/20).
__global__ __launch_bounds__(512, 4) void logits_kernel(
    const f16* __restrict__ q16, const f16* __restrict__ k16,
    const float* __restrict__ amask, __bf16* __restrict__ pu, float* __restrict__ psum)
{
    const int f = blockIdx.x;
    const int xcd = f & 7;
    const int j = f >> 3;
    const int b = xcd + 8 * (j / 20);
    const int tile = j % 20;
    const int mt = (tile < 2) ? 0 : (tile < 6) ? 1 : (tile < 12) ? 2 : 3;
    const int nt = tile - ((mt == 0) ? 0 : (mt == 1) ? 2 : (mt == 2) ? 6 : 12);
    const int m0 = mt * 256, n0 = nt * 128;
    const size_t pb = (size_t)b << 20;
    const size_t qb = (size_t)b * 1024 * 768;

    __shared__ alignas(16) f16 S[2][24 * 512];   // 48 KB dbuf
    __shared__ float rs[2][256];

    const int t = threadIdx.x, lane = t & 63, wave = t >> 6;
    const int wm = (wave & 3) * 64, wn = (wave >> 2) * 64;
    const int quad = lane >> 4, l16 = lane & 15;

    const f16* gsrc[3];
    int ldst[3];
    #pragma unroll
    for (int u = 0; u < 3; ++u) {
        int c = wave * 3 + u;
        ldst[u] = c * 512;
        const f16* base = (c < 16) ? (q16 + qb + (size_t)(m0 + c * 16 + l16) * 768)
                                   : (k16 + qb + (size_t)(n0 + (c - 16) * 16 + l16) * 768);
        gsrc[u] = base + quad * 8;
    }

    f32x4 acc[4][4] = {};
    auto stage = [&](int k0, int buf) {
        #pragma unroll
        for (int u = 0; u < 3; ++u)
            gl_lds16(gsrc[u] + k0, &S[buf][ldst[u]]);
    };
    auto compute = [&](int buf) {
        f16x8 af[4], bg[4];
        #pragma unroll
        for (int i = 0; i < 4; ++i) {
            af[i] = *(const f16x8*)&S[buf][(wm / 16 + i) * 512 + quad * 128 + l16 * 8];
            bg[i] = *(const f16x8*)&S[buf][(16 + wn / 16 + i) * 512 + quad * 128 + l16 * 8];
        }
        #pragma unroll
        for (int i = 0; i < 4; ++i)
            #pragma unroll
            for (int jj = 0; jj < 4; ++jj)
                acc[i][jj] = MFMA_F16(af[i], bg[jj], acc[i][jj]);
    };

    stage(0, 0);
    int cur = 0;
    for (int k0 = 32; k0 < 768; k0 += 32) {
        __syncthreads();
        stage(k0, cur ^ 1);
        compute(cur);
        cur ^= 1;
    }
    __syncthreads();
    compute(cur);

    float rp[4][4] = {};
    #pragma unroll
    for (int jj = 0; jj < 4; ++jj) {
        int col = n0 + wn + jj * 16 + l16;
        float am = (1.0f - amask[b * 1024 + col]) * -10000.0f;
        #pragma unroll
        for (int i = 0; i < 4; ++i)
            #pragma unroll
            for (int r = 0; r < 4; ++r) {
                int row = m0 + wm + i * 16 + quad * 4 + r;
                float s = acc[i][jj][r] + am;
                float pval = (col <= row) ? __expf(fminf(s, 80.0f)) : 0.0f;
                pu[pb + (size_t)row * 1024 + col] = (__bf16)pval;
                rp[i][r] += pval;
            }
    }
    #pragma unroll
    for (int i = 0; i < 4; ++i)
        #pragma unroll
        for (int r = 0; r < 4; ++r) {
            float v = rp[i][r];
            v += __shfl_xor(v, 1, 64);
            v += __shfl_xor(v, 2, 64);
            v += __shfl_xor(v, 4, 64);
            v += __shfl_xor(v, 8, 64);
            if (l16 == 0) rs[wn >> 6][wm + i * 16 + quad * 4 + r] = v;
        }
    __syncthreads();
    if (t < 256)
        psum[((size_t)b * 1024 + m0 + t) * 8 + nt] = rs[0][t] + rs[1][t];
}

// ---------------- K3: h = (p_u @ v) / rowsum, 256x128 tiles -----------------
// grid 768 = 8 xcd * (4 batch-groups * 24 tiles). batch = xcd+8*(j/24).
__global__ __launch_bounds__(512, 4) void pv_kernel(
    const __bf16* __restrict__ pu, const __bf16* __restrict__ vT,
    const float* __restrict__ psum, __bf16* __restrict__ h)
{
    const int f = blockIdx.x;
    const int xcd = f & 7;
    const int j = f >> 3;
    const int b = xcd + 8 * (j / 24);
    const int tile = j % 24;
    const int mt = tile / 6, nt = tile % 6;
    const int m0 = mt * 256, n0 = nt * 128;
    const size_t pb = (size_t)b << 20;
    const size_t vb = (size_t)b * 768 * 1024;

    __shared__ alignas(16) __bf16 S[2][24 * 512];   // 48 KB dbuf
    __shared__ float invl[256];

    const int t = threadIdx.x, lane = t & 63, wave = t >> 6;
    const int wm = (wave & 3) * 64, wn = (wave >> 2) * 64;
    const int quad = lane >> 4, l16 = lane & 15;

    if (t < 256) {
        int row = m0 + t;
        int lim = row >> 7;  // psum[row][nt] written only for nt <= row>>7
        const float* pr = &psum[((size_t)b * 1024 + row) * 8];
        float s = 0.f;
        #pragma unroll
        for (int n = 0; n < 8; ++n) s += (n <= lim) ? pr[n] : 0.f;
        invl[t] = 1.0f / s;
    }

    const __bf16* gsrc[3];
    int ldst[3];
    #pragma unroll
    for (int u = 0; u < 3; ++u) {
        int c = wave * 3 + u;
        ldst[u] = c * 512;
        const __bf16* base = (c < 16) ? (pu + pb + (size_t)(m0 + c * 16 + l16) * 1024)
                                      : (vT + vb + (size_t)(n0 + (c - 16) * 16 + l16) * 1024);
        gsrc[u] = base + quad * 8;
    }

    f32x4 acc[4][4] = {};
    auto stage = [&](int k0, int buf) {
        #pragma unroll
        for (int u = 0; u < 3; ++u)
            gl_lds16(gsrc[u] + k0, &S[buf][ldst[u]]);
    };
    auto compute = [&](int buf) {
        bfx8 af[4], bg[4];
        #pragma unroll
        for (int i = 0; i < 4; ++i) {
            af[i] = *(const bfx8*)&S[buf][(wm / 16 + i) * 512 + quad * 128 + l16 * 8];
            bg[i] = *(const bfx8*)&S[buf][(16 + wn / 16 + i) * 512 + quad * 128 + l16 * 8];
        }
        #pragma unroll
        for (int i = 0; i < 4; ++i)
            #pragma unroll
            for (int jj = 0; jj < 4; ++jj)
                acc[i][jj] = MFMA_BF16(af[i], bg[jj], acc[i][jj]);
    };

    const int kend = m0 + 256;  // p_u is exactly 0 above the diagonal
    stage(0, 0);
    int cur = 0;
    for (int k0 = 32; k0 < kend; k0 += 32) {
        __syncthreads();
        stage(k0, cur ^ 1);
        compute(cur);
        cur ^= 1;
    }
    __syncthreads();
    compute(cur);

    #pragma unroll
    for (int jj = 0; jj < 4; ++jj) {
        int col = n0 + wn + jj * 16 + l16;
        #pragma unroll
        for (int i = 0; i < 4; ++i)
            #pragma unroll
            for (int r = 0; r < 4; ++r) {
                int rl = wm + i * 16 + quad * 4 + r;
                h[((size_t)b * 1024 + m0 + rl) * 768 + col] = (__bf16)(acc[i][jj][r] * invl[rl]);
            }
    }
}

// ---------------- K4: out = relu(h @ W1^T + b1) @ W2^T + b2 -----------------
__global__ __launch_bounds__(256) void mlp_kernel(
    const __bf16* __restrict__ h, const float* __restrict__ W1, const float* __restrict__ b1,
    const float* __restrict__ W2, const float* __restrict__ b2, float* __restrict__ out)
{
    const int wave = threadIdx.x >> 6, lane = threadIdx.x & 63;
    const int quad = lane >> 4, l16 = lane & 15;
    const int m0 = blockIdx.x * 64 + wave * 16;

    f32x4 acc[4] = {};
    for (int k0 = 0; k0 < 768; k0 += 32) {
        bfx8 af = *(const bfx8*)&h[(size_t)(m0 + l16) * 768 + k0 + quad * 8];
        #pragma unroll
        for (int jj = 0; jj < 4; ++jj) {
            const float* wp = W1 + (size_t)(jj * 16 + l16) * 768 + k0 + quad * 8;
            f32x4 w0 = *(const f32x4*)wp;
            f32x4 w1 = *(const f32x4*)(wp + 4);
            bfx8 bg;
            #pragma unroll
            for (int e = 0; e < 4; ++e) { bg[e] = (__bf16)w0[e]; bg[e + 4] = (__bf16)w1[e]; }
            acc[jj] = MFMA_BF16(af, bg, acc[jj]);
        }
    }
    float part[4][2] = {};
    #pragma unroll
    for (int jj = 0; jj < 4; ++jj) {
        int c = jj * 16 + l16;
        float bb = b1[c];
        float w20 = W2[c], w21 = W2[64 + c];
        #pragma unroll
        for (int r = 0; r < 4; ++r) {
            float x = fmaxf(acc[jj][r] + bb, 0.f);
            part[r][0] += x * w20;
            part[r][1] += x * w21;
        }
    }
    #pragma unroll
    for (int off = 1; off < 16; off <<= 1)
        #pragma unroll
        for (int r = 0; r < 4; ++r) {
            part[r][0] += __shfl_xor(part[r][0], off, 64);
            part[r][1] += __shfl_xor(part[r][1], off, 64);
        }
    if (l16 == 0) {
        #pragma unroll
        for (int r = 0; r < 4; ++r) {
            int row = m0 + quad * 4 + r;
            out[(size_t)row * 2 + 0] = part[r][0] + b2[0];
            out[(size_t)row * 2 + 1] = part[r][1] + b2[1];
        }
    }
}

// ---------------------------------------------------------------------------
extern "C" void kernel_launch(void* const* d_in, const int* in_sizes, int n_in,
                              void* d_out, int out_size, void* d_ws, size_t ws_size,
                              hipStream_t stream)
{
    const float* hidden = (const float*)d_in[0];
    const float* amask  = (const float*)d_in[1];
    const float* Wk = (const float*)d_in[2];
    const float* bk = (const float*)d_in[3];
    const float* Wq = (const float*)d_in[4];
    const float* bq = (const float*)d_in[5];
    const float* Wv = (const float*)d_in[6];
    const float* bv = (const float*)d_in[7];
    const float* W1 = (const float*)d_in[8];
    const float* b1 = (const float*)d_in[9];
    const float* W2 = (const float*)d_in[10];
    const float* b2 = (const float*)d_in[11];
    float* out = (float*)d_out;

    char* ws = (char*)d_ws;
    const size_t MB = 1024 * 1024;
    f16* h16 = (f16*)ws;
    f16* wq16 = (f16*)(ws + 48 * MB);
    f16* wk16 = wq16 + 589824;
    f16* wv16 = wk16 + 589824;
    __bf16* pu  = (__bf16*)ws;                 // aliases h16/W16 (dead after qkv)
    float*  psum = (float*)(ws + 64 * MB);
    f16* q16 = (f16*)(ws + 66 * MB);
    f16* k16 = (f16*)(ws + 114 * MB);
    __bf16* vT = (__bf16*)(ws + 162 * MB);
    __bf16* h  = (__bf16*)(ws + 66 * MB);      // aliases q16 (dead after logits)
    const size_t NEED = 210 * MB;
    if (ws_size < NEED) {
        fprintf(stderr, "[Attn kernel] ws too small: %zu < %zu — skipping launches\n",
                ws_size, NEED);
        return;
    }

    cvt_f32_f16<<<24576, 256, 0, stream>>>(hidden, h16, 25165824);
    cvt3_w<<<dim3(576, 3), 256, 0, stream>>>(Wq, Wk, Wv, wq16, wk16, wv16);

    qkv_kernel<<<1152, 1024, 0, stream>>>(
        h16, wq16, wk16, wv16, bq, bk, bv, q16, k16, vT);
    logits_kernel<<<640, 512, 0, stream>>>(q16, k16, amask, pu, psum);
    pv_kernel<<<768, 512, 0, stream>>>(pu, vT, psum, h);
    mlp_kernel<<<512, 256, 0, stream>>>(h, W1, b1, W2, b2, out);
}

// Round 9
// 538.177 us; speedup vs baseline: 1.3793x; 1.0194x over previous
//
#include <hip/hip_runtime.h>
#include <hip/hip_bf16.h>
#include <cstdio>

// ---------------------------------------------------------------------------
// Attn_59940563583594: hidden[32,1024,768] -> QKV -> causal attn (no 1/sqrt(d))
//                      -> relu MLP(768->64) -> out[32,1024,2] fp32
// Numerics (verified R2-R8: absmax 9.8e-4 vs 3.8e-3 threshold):
//   f16 storage/MFMA for hidden/W/q/k, no-max softmax (exp clamp 80,
//   unnormalized bf16 p, fp32 row sums, normalize in PV), bf16 PV + MLP.
// R9: apply the R8 256x256/1024-thr template to logits (10 causal tiles/
//   batch, staged 369->252 MB) and pv (12 tiles/batch, 377->252 MB); tiles
//   ordered longest-K first for makespan packing at ~1.3 blocks/CU; psum
//   4 slots (nt256). cvt + cvt3 merged into one dispatch. qkv unchanged
//   (at its structural plateau ~193 us).
// ---------------------------------------------------------------------------

typedef _Float16 f16;
typedef f16    f16x8 __attribute__((ext_vector_type(8)));
typedef f16    f16x4 __attribute__((ext_vector_type(4)));
typedef __bf16 bfx8  __attribute__((ext_vector_type(8)));
typedef float  f32x4 __attribute__((ext_vector_type(4)));

#define MFMA_F16(a,b,c)  __builtin_amdgcn_mfma_f32_16x16x32_f16((a),(b),(c),0,0,0)
#define MFMA_BF16(a,b,c) __builtin_amdgcn_mfma_f32_16x16x32_bf16((a),(b),(c),0,0,0)

static constexpr int LDT2 = 264;  // qkv v-transpose stride (128e x 256s)

__device__ __forceinline__ void gl_lds16(const void* g, void* l) {
    __builtin_amdgcn_global_load_lds(
        (const __attribute__((address_space(1))) void*)g,
        (__attribute__((address_space(3))) void*)l, 16, 0, 0);
}

// ---------------- fp32 -> f16 convert (hidden + 3 weights, one dispatch) ----
__global__ __launch_bounds__(256) void cvt_all(
    const float* __restrict__ hidden,
    const float* __restrict__ Wq, const float* __restrict__ Wk, const float* __restrict__ Wv,
    f16* __restrict__ h16, f16* __restrict__ oq, f16* __restrict__ ok, f16* __restrict__ ov)
{
    const int bid = blockIdx.x;
    const float* src;
    f16* dst;
    int base;
    if (bid < 24576) {
        src = hidden; dst = h16;
        base = (bid * 256 + threadIdx.x) * 4;
    } else {
        int wz = (bid - 24576) / 576, wb = (bid - 24576) % 576;
        src = (wz == 0) ? Wq : (wz == 1) ? Wk : Wv;
        dst = (wz == 0) ? oq : (wz == 1) ? ok : ov;
        base = (wb * 256 + threadIdx.x) * 4;
    }
    f32x4 v = *(const f32x4*)(src + base);
    f16x4 o;
    #pragma unroll
    for (int e = 0; e < 4; ++e) o[e] = (f16)v[e];
    *(f16x4*)(dst + base) = o;
}

// ---------------- K1: fused q,k,v projections, 256x256 tiles (R8) -----------
__global__ __launch_bounds__(1024, 4) void qkv_kernel(
    const f16* __restrict__ h16,
    const f16* __restrict__ wq, const f16* __restrict__ wk, const f16* __restrict__ wv,
    const float* __restrict__ bq, const float* __restrict__ bk, const float* __restrict__ bv,
    f16* __restrict__ q16, f16* __restrict__ k16, __bf16* __restrict__ vT)
{
    const int f = blockIdx.x;
    const int xcd = f & 7;
    const int j = f >> 3;
    const int nt = j % 3;
    const int z  = (j / 3) % 3;
    const int mi = j / 9;
    const int mt = xcd + 8 * mi;
    const int m0 = mt * 256, n0 = nt * 256;

    const f16* W = (z == 0) ? wq : (z == 1) ? wk : wv;
    const float* bias = (z == 0) ? bq : (z == 1) ? bk : bv;

    __shared__ alignas(16) char smem[67584];
    f16 (*S)[16384] = (f16 (*)[16384])smem;
    __bf16* Tb = (__bf16*)smem;

    const int t = threadIdx.x, lane = t & 63, wave = t >> 6;
    const int wm = (wave & 3) * 64, wn = (wave >> 2) * 64;
    const int quad = lane >> 4, l16 = lane & 15;

    const f16* gsrc[2];
    int ldst[2];
    #pragma unroll
    for (int u = 0; u < 2; ++u) {
        int c = wave * 2 + u;
        ldst[u] = c * 512;
        int row = (c < 16) ? (m0 + c * 16 + l16) : (n0 + (c - 16) * 16 + l16);
        const f16* base = (c < 16) ? h16 : W;
        gsrc[u] = base + (size_t)row * 768 + quad * 8;
    }

    f32x4 acc[4][4] = {};
    auto stage = [&](int k0, int buf) {
        #pragma unroll
        for (int u = 0; u < 2; ++u)
            gl_lds16(gsrc[u] + k0, &S[buf][ldst[u]]);
    };
    auto compute = [&](int buf) {
        f16x8 af[4], bg[4];
        #pragma unroll
        for (int i = 0; i < 4; ++i) {
            af[i] = *(const f16x8*)&S[buf][(wm / 16 + i) * 512 + quad * 128 + l16 * 8];
            bg[i] = *(const f16x8*)&S[buf][(16 + wn / 16 + i) * 512 + quad * 128 + l16 * 8];
        }
        #pragma unroll
        for (int i = 0; i < 4; ++i)
            #pragma unroll
            for (int jj = 0; jj < 4; ++jj)
                acc[i][jj] = MFMA_F16(af[i], bg[jj], acc[i][jj]);
    };

    stage(0, 0);
    int cur = 0;
    for (int k0 = 32; k0 < 768; k0 += 32) {
        __syncthreads();
        stage(k0, cur ^ 1);
        compute(cur);
        cur ^= 1;
    }
    __syncthreads();
    compute(cur);

    if (z < 2) {
        f16* out = z ? k16 : q16;
        #pragma unroll
        for (int jj = 0; jj < 4; ++jj) {
            int col = n0 + wn + jj * 16 + l16;
            float bb = bias[col];
            #pragma unroll
            for (int i = 0; i < 4; ++i)
                #pragma unroll
                for (int r = 0; r < 4; ++r) {
                    int row = m0 + wm + i * 16 + quad * 4 + r;  // D: col=lane&15, row=quad*4+reg
                    out[(size_t)row * 768 + col] = (f16)(acc[i][jj][r] + bb);
                }
        }
    } else {
        const int bofs = (m0 >> 10) * 768;
        const int s0 = m0 & 1023;
        #pragma unroll
        for (int half = 0; half < 2; ++half) {
            __syncthreads();
            if ((wn >> 7) == half) {
                int wnl = wn & 127;
                #pragma unroll
                for (int jj = 0; jj < 4; ++jj) {
                    int el = wnl + jj * 16 + l16;
                    float bb = bias[n0 + half * 128 + el];
                    #pragma unroll
                    for (int i = 0; i < 4; ++i)
                        #pragma unroll
                        for (int r = 0; r < 4; ++r) {
                            int sl = wm + i * 16 + quad * 4 + r;
                            Tb[el * LDT2 + sl] = (__bf16)(acc[i][jj][r] + bb);
                        }
                }
            }
            __syncthreads();
            const int ch = (t & 31) * 8;
            const int rbase = t >> 5;
            #pragma unroll
            for (int p = 0; p < 4; ++p) {
                int r2 = rbase + p * 32;
                bfx8 val = *(const bfx8*)&Tb[r2 * LDT2 + ch];
                *(bfx8*)&vT[(size_t)(bofs + n0 + half * 128 + r2) * 1024 + s0 + ch] = val;
            }
        }
    }
}

// ---------------- K2: p_u = exp(q@k^T + mask), 256x256 causal tiles ---------
// grid 320 = 8 xcd * (4 batch-groups * 10 causal tiles), longest (mt=3) first.
__global__ __launch_bounds__(1024, 4) void logits_kernel(
    const f16* __restrict__ q16, const f16* __restrict__ k16,
    const float* __restrict__ amask, __bf16* __restrict__ pu, float* __restrict__ psum)
{
    const int f = blockIdx.x;
    const int xcd = f & 7;
    const int j = f >> 3;
    const int b = xcd + 8 * (j / 10);
    const int tile = j % 10;
    int mt, nt;
    if (tile < 4)      { mt = 3; nt = tile; }
    else if (tile < 7) { mt = 2; nt = tile - 4; }
    else if (tile < 9) { mt = 1; nt = tile - 7; }
    else               { mt = 0; nt = 0; }
    const int m0 = mt * 256, n0 = nt * 256;
    const size_t pb = (size_t)b << 20;
    const size_t qb = (size_t)b * 1024 * 768;

    __shared__ alignas(16) f16 S[2][32 * 512];   // 64 KB dbuf
    __shared__ float rs[4][256];

    const int t = threadIdx.x, lane = t & 63, wave = t >> 6;
    const int wm = (wave & 3) * 64, wn = (wave >> 2) * 64;
    const int quad = lane >> 4, l16 = lane & 15;

    const f16* gsrc[2];
    int ldst[2];
    #pragma unroll
    for (int u = 0; u < 2; ++u) {
        int c = wave * 2 + u;
        ldst[u] = c * 512;
        const f16* base = (c < 16) ? (q16 + qb + (size_t)(m0 + c * 16 + l16) * 768)
                                   : (k16 + qb + (size_t)(n0 + (c - 16) * 16 + l16) * 768);
        gsrc[u] = base + quad * 8;
    }

    f32x4 acc[4][4] = {};
    auto stage = [&](int k0, int buf) {
        #pragma unroll
        for (int u = 0; u < 2; ++u)
            gl_lds16(gsrc[u] + k0, &S[buf][ldst[u]]);
    };
    auto compute = [&](int buf) {
        f16x8 af[4], bg[4];
        #pragma unroll
        for (int i = 0; i < 4; ++i) {
            af[i] = *(const f16x8*)&S[buf][(wm / 16 + i) * 512 + quad * 128 + l16 * 8];
            bg[i] = *(const f16x8*)&S[buf][(16 + wn / 16 + i) * 512 + quad * 128 + l16 * 8];
        }
        #pragma unroll
        for (int i = 0; i < 4; ++i)
            #pragma unroll
            for (int jj = 0; jj < 4; ++jj)
                acc[i][jj] = MFMA_F16(af[i], bg[jj], acc[i][jj]);
    };

    stage(0, 0);
    int cur = 0;
    for (int k0 = 32; k0 < 768; k0 += 32) {
        __syncthreads();
        stage(k0, cur ^ 1);
        compute(cur);
        cur ^= 1;
    }
    __syncthreads();
    compute(cur);

    float rp[4][4] = {};
    #pragma unroll
    for (int jj = 0; jj < 4; ++jj) {
        int col = n0 + wn + jj * 16 + l16;
        float am = (1.0f - amask[b * 1024 + col]) * -10000.0f;
        #pragma unroll
        for (int i = 0; i < 4; ++i)
            #pragma unroll
            for (int r = 0; r < 4; ++r) {
                int row = m0 + wm + i * 16 + quad * 4 + r;
                float s = acc[i][jj][r] + am;
                float pval = (col <= row) ? __expf(fminf(s, 80.0f)) : 0.0f;
                pu[pb + (size_t)row * 1024 + col] = (__bf16)pval;
                rp[i][r] += pval;
            }
    }
    #pragma unroll
    for (int i = 0; i < 4; ++i)
        #pragma unroll
        for (int r = 0; r < 4; ++r) {
            float v = rp[i][r];
            v += __shfl_xor(v, 1, 64);
            v += __shfl_xor(v, 2, 64);
            v += __shfl_xor(v, 4, 64);
            v += __shfl_xor(v, 8, 64);   // sum over l16 group
            if (l16 == 0) rs[wn >> 6][wm + i * 16 + quad * 4 + r] = v;
        }
    __syncthreads();
    if (t < 256)
        psum[((size_t)b * 1024 + m0 + t) * 4 + nt] =
            rs[0][t] + rs[1][t] + rs[2][t] + rs[3][t];
}

// ---------------- K3: h = (p_u @ v) / rowsum, 256x256 tiles -----------------
// grid 384 = 8 xcd * (4 batch-groups * 12 tiles), longest (mt=3) first.
__global__ __launch_bounds__(1024, 4) void pv_kernel(
    const __bf16* __restrict__ pu, const __bf16* __restrict__ vT,
    const float* __restrict__ psum, __bf16* __restrict__ h)
{
    const int f = blockIdx.x;
    const int xcd = f & 7;
    const int j = f >> 3;
    const int b = xcd + 8 * (j / 12);
    const int tile = j % 12;
    const int mt = 3 - tile / 3, nt = tile % 3;
    const int m0 = mt * 256, n0 = nt * 256;
    const size_t pb = (size_t)b << 20;
    const size_t vb = (size_t)b * 768 * 1024;

    __shared__ alignas(16) __bf16 S[2][32 * 512];   // 64 KB dbuf
    __shared__ float invl[256];

    const int t = threadIdx.x, lane = t & 63, wave = t >> 6;
    const int wm = (wave & 3) * 64, wn = (wave >> 2) * 64;
    const int quad = lane >> 4, l16 = lane & 15;

    if (t < 256) {
        int row = m0 + t;
        int lim = row >> 8;  // psum[row][nt] written only for nt <= row>>8
        const float* pr = &psum[((size_t)b * 1024 + row) * 4];
        float s = 0.f;
        #pragma unroll
        for (int n = 0; n < 4; ++n) s += (n <= lim) ? pr[n] : 0.f;
        invl[t] = 1.0f / s;
    }

    const __bf16* gsrc[2];
    int ldst[2];
    #pragma unroll
    for (int u = 0; u < 2; ++u) {
        int c = wave * 2 + u;
        ldst[u] = c * 512;
        const __bf16* base = (c < 16) ? (pu + pb + (size_t)(m0 + c * 16 + l16) * 1024)
                                      : (vT + vb + (size_t)(n0 + (c - 16) * 16 + l16) * 1024);
        gsrc[u] = base + quad * 8;
    }

    f32x4 acc[4][4] = {};
    auto stage = [&](int k0, int buf) {
        #pragma unroll
        for (int u = 0; u < 2; ++u)
            gl_lds16(gsrc[u] + k0, &S[buf][ldst[u]]);
    };
    auto compute = [&](int buf) {
        bfx8 af[4], bg[4];
        #pragma unroll
        for (int i = 0; i < 4; ++i) {
            af[i] = *(const bfx8*)&S[buf][(wm / 16 + i) * 512 + quad * 128 + l16 * 8];
            bg[i] = *(const bfx8*)&S[buf][(16 + wn / 16 + i) * 512 + quad * 128 + l16 * 8];
        }
        #pragma unroll
        for (int i = 0; i < 4; ++i)
            #pragma unroll
            for (int jj = 0; jj < 4; ++jj)
                acc[i][jj] = MFMA_BF16(af[i], bg[jj], acc[i][jj]);
    };

    const int kend = m0 + 256;  // p_u is exactly 0 above the diagonal
    stage(0, 0);
    int cur = 0;
    for (int k0 = 32; k0 < kend; k0 += 32) {
        __syncthreads();
        stage(k0, cur ^ 1);
        compute(cur);
        cur ^= 1;
    }
    __syncthreads();
    compute(cur);

    #pragma unroll
    for (int jj = 0; jj < 4; ++jj) {
        int col = n0 + wn + jj * 16 + l16;
        #pragma unroll
        for (int i = 0; i < 4; ++i)
            #pragma unroll
            for (int r = 0; r < 4; ++r) {
                int rl = wm + i * 16 + quad * 4 + r;
                h[((size_t)b * 1024 + m0 + rl) * 768 + col] = (__bf16)(acc[i][jj][r] * invl[rl]);
            }
    }
}

// ---------------- K4: out = relu(h @ W1^T + b1) @ W2^T + b2 -----------------
__global__ __launch_bounds__(256) void mlp_kernel(
    const __bf16* __restrict__ h, const float* __restrict__ W1, const float* __restrict__ b1,
    const float* __restrict__ W2, const float* __restrict__ b2, float* __restrict__ out)
{
    const int wave = threadIdx.x >> 6, lane = threadIdx.x & 63;
    const int quad = lane >> 4, l16 = lane & 15;
    const int m0 = blockIdx.x * 64 + wave * 16;

    f32x4 acc[4] = {};
    for (int k0 = 0; k0 < 768; k0 += 32) {
        bfx8 af = *(const bfx8*)&h[(size_t)(m0 + l16) * 768 + k0 + quad * 8];
        #pragma unroll
        for (int jj = 0; jj < 4; ++jj) {
            const float* wp = W1 + (size_t)(jj * 16 + l16) * 768 + k0 + quad * 8;
            f32x4 w0 = *(const f32x4*)wp;
            f32x4 w1 = *(const f32x4*)(wp + 4);
            bfx8 bg;
            #pragma unroll
            for (int e = 0; e < 4; ++e) { bg[e] = (__bf16)w0[e]; bg[e + 4] = (__bf16)w1[e]; }
            acc[jj] = MFMA_BF16(af, bg, acc[jj]);
        }
    }
    float part[4][2] = {};
    #pragma unroll
    for (int jj = 0; jj < 4; ++jj) {
        int c = jj * 16 + l16;
        float bb = b1[c];
        float w20 = W2[c], w21 = W2[64 + c];
        #pragma unroll
        for (int r = 0; r < 4; ++r) {
            float x = fmaxf(acc[jj][r] + bb, 0.f);
            part[r][0] += x * w20;
            part[r][1] += x * w21;
        }
    }
    #pragma unroll
    for (int off = 1; off < 16; off <<= 1)
        #pragma unroll
        for (int r = 0; r < 4; ++r) {
            part[r][0] += __shfl_xor(part[r][0], off, 64);
            part[r][1] += __shfl_xor(part[r][1], off, 64);
        }
    if (l16 == 0) {
        #pragma unroll
        for (int r = 0; r < 4; ++r) {
            int row = m0 + quad * 4 + r;
            out[(size_t)row * 2 + 0] = part[r][0] + b2[0];
            out[(size_t)row * 2 + 1] = part[r][1] + b2[1];
        }
    }
}

// ---------------------------------------------------------------------------
extern "C" void kernel_launch(void* const* d_in, const int* in_sizes, int n_in,
                              void* d_out, int out_size, void* d_ws, size_t ws_size,
                              hipStream_t stream)
{
    const float* hidden = (const float*)d_in[0];
    const float* amask  = (const float*)d_in[1];
    const float* Wk = (const float*)d_in[2];
    const float* bk = (const float*)d_in[3];
    const float* Wq = (const float*)d_in[4];
    const float* bq = (const float*)d_in[5];
    const float* Wv = (const float*)d_in[6];
    const float* bv = (const float*)d_in[7];
    const float* W1 = (const float*)d_in[8];
    const float* b1 = (const float*)d_in[9];
    const float* W2 = (const float*)d_in[10];
    const float* b2 = (const float*)d_in[11];
    float* out = (float*)d_out;

    char* ws = (char*)d_ws;
    const size_t MB = 1024 * 1024;
    f16* h16 = (f16*)ws;
    f16* wq16 = (f16*)(ws + 48 * MB);
    f16* wk16 = wq16 + 589824;
    f16* wv16 = wk16 + 589824;
    __bf16* pu  = (__bf16*)ws;                 // aliases h16/W16 (dead after qkv)
    float*  psum = (float*)(ws + 64 * MB);     // 32*1024*4 fp32 = 512 KB
    f16* q16 = (f16*)(ws + 66 * MB);
    f16* k16 = (f16*)(ws + 114 * MB);
    __bf16* vT = (__bf16*)(ws + 162 * MB);
    __bf16* h  = (__bf16*)(ws + 66 * MB);      // aliases q16 (dead after logits)
    const size_t NEED = 210 * MB;
    if (ws_size < NEED) {
        fprintf(stderr, "[Attn kernel] ws too small: %zu < %zu — skipping launches\n",
                ws_size, NEED);
        return;
    }

    cvt_all<<<24576 + 1728, 256, 0, stream>>>(
        hidden, Wq, Wk, Wv, h16, wq16, wk16, wv16);

    qkv_kernel<<<1152, 1024, 0, stream>>>(
        h16, wq16, wk16, wv16, bq, bk, bv, q16, k16, vT);
    logits_kernel<<<320, 1024, 0, stream>>>(q16, k16, amask, pu, psum);
    pv_kernel<<<384, 1024, 0, stream>>>(pu, vT, psum, h);
    mlp_kernel<<<512, 256, 0, stream>>>(h, W1, b1, W2, b2, out);
}